// Round 9
// baseline (4339.503 us; speedup 1.0000x reference)
//
#include <hip/hip_runtime.h>
#include <math.h>

#define DIM    768
#define BATCH  1024
#define NANS   128000
#define NT128  1000             // 128-answer shortlist tiles
#define CAND2  (NT128*10)       // 10000 shortlist candidates per row
#define NWORDS 4000             // mask bit-words per batch row (128000/32)

typedef short  bf16x8 __attribute__((ext_vector_type(8)));
typedef float  f32x4  __attribute__((ext_vector_type(4)));

__device__ __forceinline__ short f2bf(float x)
{
    unsigned u = __builtin_bit_cast(unsigned, x);
    u += 0x7fffu + ((u >> 16) & 1u);          // RNE (no NaN inputs here)
    return (short)(u >> 16);
}

__device__ __forceinline__ void gload16(const void* g, void* l)
{
    __builtin_amdgcn_global_load_lds(
        (const __attribute__((address_space(1))) void*)g,
        (__attribute__((address_space(3))) void*)l, 16, 0, 0);
}

// sorted-descending top-10 insertion (static indices only)
__device__ __forceinline__ void ins10(float (&s)[10], int (&ix)[10], float v, int vi)
{
    if (v > s[9] || (v == s[9] && vi < ix[9])) {
        s[9] = v; ix[9] = vi;
        #pragma unroll
        for (int q = 9; q > 0; --q) {
            bool sw = (s[q] > s[q-1]) || (s[q] == s[q-1] && ix[q] < ix[q-1]);
            float ts = s[q-1]; int ti = ix[q-1];
            s[q-1] = sw ? s[q] : s[q-1]; ix[q-1] = sw ? ix[q] : ix[q-1];
            s[q]   = sw ? ts   : s[q];   ix[q]   = sw ? ti   : ix[q];
        }
    }
}

__device__ __forceinline__ void ins16(float (&s)[16], int (&ix)[16], float v, int vi)
{
    if (v > s[15] || (v == s[15] && vi < ix[15])) {
        s[15] = v; ix[15] = vi;
        #pragma unroll
        for (int q = 15; q > 0; --q) {
            bool sw = (s[q] > s[q-1]) || (s[q] == s[q-1] && ix[q] < ix[q-1]);
            float ts = s[q-1]; int ti = ix[q-1];
            s[q-1] = sw ? s[q] : s[q-1]; ix[q-1] = sw ? ix[q] : ix[q-1];
            s[q]   = sw ? ts   : s[q];   ix[q]   = sw ? ti   : ix[q];
        }
    }
}

// ---------------------------------------------------------------------------
// Upstream GEMM: C[M,N] = A[M,K] @ W[N,K]^T + bias   (fp32)
// ---------------------------------------------------------------------------
__global__ __launch_bounds__(256, 2) void gemm_bias_k(
    const float* __restrict__ A, int lda,
    const float* __restrict__ W,
    const float* __restrict__ bias,
    float* __restrict__ C, int ldc, int K)
{
    __shared__ float as[32][68];
    __shared__ float bs[32][68];
    int m0 = blockIdx.x * 64, n0 = blockIdx.y * 64;
    int tid = threadIdx.x;
    int tm = tid & 15, tn = tid >> 4;
    int sr = tid >> 3, skq = tid & 7;
    float acc[4][4] = {};
    for (int k0 = 0; k0 < K; k0 += 32) {
        __syncthreads();
        #pragma unroll
        for (int p = 0; p < 2; ++p) {
            int r = sr + 32 * p;
            float4 av = *(const float4*)&A[(size_t)(m0 + r) * lda + k0 + skq * 4];
            as[skq*4+0][r] = av.x; as[skq*4+1][r] = av.y;
            as[skq*4+2][r] = av.z; as[skq*4+3][r] = av.w;
            float4 wv = *(const float4*)&W[(size_t)(n0 + r) * K + k0 + skq * 4];
            bs[skq*4+0][r] = wv.x; bs[skq*4+1][r] = wv.y;
            bs[skq*4+2][r] = wv.z; bs[skq*4+3][r] = wv.w;
        }
        __syncthreads();
        #pragma unroll 8
        for (int k = 0; k < 32; ++k) {
            float a4[4], b4[4];
            *(float4*)a4 = *(const float4*)&as[k][tm*4];
            *(float4*)b4 = *(const float4*)&bs[k][tn*4];
            #pragma unroll
            for (int i = 0; i < 4; ++i)
                #pragma unroll
                for (int j = 0; j < 4; ++j)
                    acc[i][j] = fmaf(a4[i], b4[j], acc[i][j]);
        }
    }
    float4 bv4 = *(const float4*)&bias[n0 + tn*4];
    #pragma unroll
    for (int i = 0; i < 4; ++i) {
        float4 c4;
        c4.x = acc[i][0] + bv4.x; c4.y = acc[i][1] + bv4.y;
        c4.z = acc[i][2] + bv4.z; c4.w = acc[i][3] + bv4.w;
        *(float4*)&C[(size_t)(m0 + tm*4 + i) * ldc + n0 + tn*4] = c4;
    }
}

// ---------------------------------------------------------------------------
__global__ void copy_visual_k(const float* __restrict__ src, float* __restrict__ dst)
{
    int idx = blockIdx.x * 256 + threadIdx.x;          // float4 index
    const int total = BATCH * (DIM / 4);
    for (; idx < total; idx += 512 * 256) {
        int b = idx / (DIM / 4), c = idx % (DIM / 4);
        ((float4*)dst)[(size_t)b * (1536 / 4) + c] = ((const float4*)src)[idx];
    }
}

// ---------------------------------------------------------------------------
__device__ __forceinline__ float block_sum(float v, float* red)
{
    #pragma unroll
    for (int o = 32; o; o >>= 1) v += __shfl_down(v, o);
    if ((threadIdx.x & 63) == 0) red[threadIdx.x >> 6] = v;
    __syncthreads();
    float r = red[0] + red[1] + red[2] + red[3];
    __syncthreads();
    return r;
}

__global__ __launch_bounds__(256) void ln_gelu_k(float* __restrict__ H,
        const float* __restrict__ g, const float* __restrict__ b)
{
    __shared__ float red[4];
    int row = blockIdx.x, tid = threadIdx.x;
    float* hr = H + (size_t)row * DIM;
    float v0 = hr[tid], v1 = hr[tid + 256], v2 = hr[tid + 512];
    float mu = block_sum(v0 + v1 + v2, red) * (1.0f / 768.0f);
    float d0 = v0 - mu, d1 = v1 - mu, d2 = v2 - mu;
    float var = block_sum(d0*d0 + d1*d1 + d2*d2, red) * (1.0f / 768.0f);
    float rinv = 1.0f / sqrtf(var + 1e-5f);
    #pragma unroll
    for (int q = 0; q < 3; ++q) {
        int d = tid + 256 * q;
        float dd = (q == 0 ? d0 : (q == 1 ? d1 : d2));
        float y = dd * rinv * g[d] + b[d];
        hr[d] = 0.5f * y * (1.0f + erff(y * 0.70710678118654752f));
    }
}

// l2-normalize P in place, also emit bf16 copy
__global__ __launch_bounds__(256) void l2norm_bf_k(float* __restrict__ P,
        short* __restrict__ Pb)
{
    __shared__ float red[4];
    int row = blockIdx.x, tid = threadIdx.x;
    float* pr = P + (size_t)row * DIM;
    short* pb = Pb + (size_t)row * DIM;
    float v0 = pr[tid], v1 = pr[tid + 256], v2 = pr[tid + 512];
    float ss = block_sum(v0*v0 + v1*v1 + v2*v2, red);
    float inv = 1.0f / fmaxf(sqrtf(ss), 1e-12f);
    v0 *= inv; v1 *= inv; v2 *= inv;
    pr[tid] = v0; pr[tid + 256] = v1; pr[tid + 512] = v2;
    pb[tid] = f2bf(v0); pb[tid + 256] = f2bf(v1); pb[tid + 512] = f2bf(v2);
}

// ---------------------------------------------------------------------------
// prep_ans: fp64 row norm -> inv64[row]; unit-normalized bf16 rows into AB.
// ---------------------------------------------------------------------------
__global__ __launch_bounds__(256) void prep_ans_k(
    const float* __restrict__ ANS, int row0, int nrows,
    double* __restrict__ inv64, short* __restrict__ AB)
{
    int r = blockIdx.x * 4 + (threadIdx.x >> 6);
    if (r >= nrows) return;
    int row = row0 + r;
    int lane = threadIdx.x & 63;
    const float4* a4 = (const float4*)(ANS + (size_t)row * DIM);
    float4 x0 = a4[lane], x1 = a4[lane + 64], x2 = a4[lane + 128];
    double ss = (double)x0.x*x0.x + (double)x0.y*x0.y + (double)x0.z*x0.z + (double)x0.w*x0.w
              + (double)x1.x*x1.x + (double)x1.y*x1.y + (double)x1.z*x1.z + (double)x1.w*x1.w
              + (double)x2.x*x2.x + (double)x2.y*x2.y + (double)x2.z*x2.z + (double)x2.w*x2.w;
    #pragma unroll
    for (int o = 32; o; o >>= 1) ss += __shfl_xor(ss, o);
    double inv = 1.0 / fmax(sqrt(ss), 1e-12);
    if (lane == 0) inv64[row] = inv;
    float invf = (float)inv;
    short* ob = AB + (size_t)r * DIM;
    ushort4 o0, o1, o2;
    o0.x = (unsigned short)f2bf(x0.x*invf); o0.y = (unsigned short)f2bf(x0.y*invf);
    o0.z = (unsigned short)f2bf(x0.z*invf); o0.w = (unsigned short)f2bf(x0.w*invf);
    o1.x = (unsigned short)f2bf(x1.x*invf); o1.y = (unsigned short)f2bf(x1.y*invf);
    o1.z = (unsigned short)f2bf(x1.z*invf); o1.w = (unsigned short)f2bf(x1.w*invf);
    o2.x = (unsigned short)f2bf(x2.x*invf); o2.y = (unsigned short)f2bf(x2.y*invf);
    o2.z = (unsigned short)f2bf(x2.z*invf); o2.w = (unsigned short)f2bf(x2.w*invf);
    *(ushort4*)&ob[lane * 4]           = o0;
    *(ushort4*)&ob[(lane + 64) * 4]    = o1;
    *(ushort4*)&ob[(lane + 128) * 4]   = o2;
}

// ---------------------------------------------------------------------------
// prep_mask: float mask [1024][128000] -> bits [1024][4000]
// ---------------------------------------------------------------------------
__global__ __launch_bounds__(256) void prep_mask_k(
    const float* __restrict__ mask, unsigned* __restrict__ bits)
{
    int row = blockIdx.x;
    const float* mr = mask + (size_t)row * NANS;
    unsigned* br = bits + (size_t)row * NWORDS;
    for (int w = threadIdx.x; w < NWORDS; w += 256) {
        const float4* p = (const float4*)(mr + w * 32);
        unsigned b = 0;
        #pragma unroll
        for (int q = 0; q < 8; ++q) {
            float4 v = p[q];
            b |= ((unsigned)(v.x != 0.f)) << (q*4+0);
            b |= ((unsigned)(v.y != 0.f)) << (q*4+1);
            b |= ((unsigned)(v.z != 0.f)) << (q*4+2);
            b |= ((unsigned)(v.w != 0.f)) << (q*4+3);
        }
        br[w] = b;
    }
}

// ---------------------------------------------------------------------------
// big4_k: m97-structure MFMA GEMM + shortlist.
// 256 threads / 4 waves; tile 128 answers x 128 batch; BK=32; 24 K-steps;
// global_load_lds(16) staging into linear LDS [row][32]; 2 barriers/K-step.
// Register-cap history (2nd launch_bounds arg = min BLOCKS/CU, CUDA-style):
//   (512,4) cap 64  -> acc spill, 8-11 GB scratch writes   [R5]
//   (512,2)/none cap 128 -> no spill but VALU-bloat codegen [R6/R7/R8: 2-3.5ms]
//   (256,1) cap 512 -> allocator free to match m97's VGPR 164 + AGPR 64.
// ---------------------------------------------------------------------------
__global__ __launch_bounds__(256, 1) void big4_k(
    const short* __restrict__ Pb,       // [1024][768] unit-norm bf16
    const short* __restrict__ AB,       // chunk rows, unit-norm bf16
    const unsigned* __restrict__ bits,  // [1024][4000]
    float* __restrict__ cs, int* __restrict__ ci,
    int t128_0, int nt128)
{
    __shared__ __align__(16) char smem[35840];
    short* a_sh = (short*)smem;                 // [128][32] = 8192 B
    short* b_sh = (short*)(smem + 8192);        // [128][32] = 8192 B
    unsigned* mb = (unsigned*)(smem + 33792);   // [128][4]  = 2048 B
    float* scl = (float*)smem;                  // reuse: [64][132] = 33792 B
    float* ms  = (float*)smem;                  // reuse: [128][20]
    int*   mi  = (int*)(smem + 10240);          // reuse: [128][20]

    // XCD swizzle: blocks on one XCD share answer tiles (nwg % 8 == 0)
    int bid = blockIdx.x;
    int v = (bid & 7) * nt128 + (bid >> 3);
    int at = v >> 3, bt = v & 7;
    int gt = t128_0 + at;                       // global 128-tile id
    int a0l = at * 128, a0g = gt * 128, b0 = bt * 128;

    int t = threadIdx.x;
    int lane = t & 63, wid = t >> 6;
    int wm = wid & 1, wn = wid >> 1;            // 2x2 wave grid of 64x64
    int lr = lane & 15, lg = lane >> 4;

    // stage mask bits: 128 rows x 4 words
    mb[t]       = bits[(size_t)(b0 + (t >> 2)) * NWORDS + gt * 4 + (t & 3)];
    mb[t + 256] = bits[(size_t)(b0 + 64 + (t >> 2)) * NWORDS + gt * 4 + (t & 3)];

    // staging addresses: chunk c of 16 B; row = c>>2, seg = c&3; thread owns
    // chunks t (rows 0-63) and t+256 (rows 64-127) for both A and B.
    const char* gA0 = (const char*)(AB + (size_t)(a0l + (t >> 2)) * DIM + (t & 3) * 8);
    const char* gA1 = (const char*)(AB + (size_t)(a0l + 64 + (t >> 2)) * DIM + (t & 3) * 8);
    const char* gB0 = (const char*)(Pb + (size_t)(b0 + (t >> 2)) * DIM + (t & 3) * 8);
    const char* gB1 = (const char*)(Pb + (size_t)(b0 + 64 + (t >> 2)) * DIM + (t & 3) * 8);
    char* la0 = (char*)a_sh + t * 16;
    char* la1 = (char*)a_sh + 4096 + t * 16;
    char* lb0 = (char*)b_sh + t * 16;
    char* lb1 = (char*)b_sh + 4096 + t * 16;

    f32x4 acc[4][4];
    #pragma unroll
    for (int i = 0; i < 4; ++i)
        #pragma unroll
        for (int j = 0; j < 4; ++j)
            acc[i][j] = (f32x4){0.f, 0.f, 0.f, 0.f};

    for (int kt = 0; kt < 24; ++kt) {
        int kb = kt * 64;                       // byte offset in a 768-short row
        gload16(gA0 + kb, la0);
        gload16(gA1 + kb, la1);
        gload16(gB0 + kb, lb0);
        gload16(gB1 + kb, lb1);
        __syncthreads();                        // drain vmcnt + barrier
        bf16x8 af[4], bg[4];
        #pragma unroll
        for (int mt = 0; mt < 4; ++mt)
            af[mt] = *(const bf16x8*)(a_sh + (wm*64 + mt*16 + lr) * 32 + lg*8);
        #pragma unroll
        for (int nt = 0; nt < 4; ++nt)
            bg[nt] = *(const bf16x8*)(b_sh + (wn*64 + nt*16 + lr) * 32 + lg*8);
        #pragma unroll
        for (int mt = 0; mt < 4; ++mt)
            #pragma unroll
            for (int nt = 0; nt < 4; ++nt)
                acc[mt][nt] = __builtin_amdgcn_mfma_f32_16x16x32_bf16(
                    af[mt], bg[nt], acc[mt][nt], 0, 0, 0);
        __syncthreads();                        // reads done before next stage
    }

    // ---- epilogue: bitmask + per-column top-10 over 128 answers ----
    float s10[10]; int i10[10];
    #pragma unroll
    for (int q = 0; q < 10; ++q) { s10[q] = -INFINITY; i10[q] = 0x7fffffff; }
    int col = t & 127, qt = t >> 7;             // qt 0..1: 32 answers each

    for (int c = 0; c < 2; ++c) {               // 64-answer chunks
        __syncthreads();
        if (wm == c) {                          // 2 waves dump their quadrants
            #pragma unroll
            for (int nt = 0; nt < 4; ++nt) {
                int lcol = wn * 64 + nt * 16 + lr;
                #pragma unroll
                for (int mt = 0; mt < 4; ++mt) {
                    int lrow = mt * 16 + lg * 4;
                    scl[(lrow + 0) * 132 + lcol] = acc[mt][nt][0];
                    scl[(lrow + 1) * 132 + lcol] = acc[mt][nt][1];
                    scl[(lrow + 2) * 132 + lcol] = acc[mt][nt][2];
                    scl[(lrow + 3) * 132 + lcol] = acc[mt][nt][3];
                }
            }
        }
        __syncthreads();
        unsigned wv = mb[col * 4 + c * 2 + qt];
        #pragma unroll
        for (int i = 0; i < 32; ++i) {
            int lrow = qt * 32 + i;
            float sc = scl[lrow * 132 + col];
            sc = ((wv >> i) & 1u) ? sc : 0.0f;
            ins10(s10, i10, sc, a0g + c * 64 + lrow);
        }
    }

    __syncthreads();                            // scl dead; reuse for merge
    #pragma unroll
    for (int k = 0; k < 10; ++k) {
        ms[col * 20 + qt * 10 + k] = s10[k];
        mi[col * 20 + qt * 10 + k] = i10[k];
    }
    __syncthreads();
    if (t < 128) {
        float fs[10]; int fi[10];
        #pragma unroll
        for (int q = 0; q < 10; ++q) { fs[q] = -INFINITY; fi[q] = 0x7fffffff; }
        for (int j = 0; j < 20; ++j)
            ins10(fs, fi, ms[t * 20 + j], mi[t * 20 + j]);
        size_t base = ((size_t)(b0 + t) * NT128 + gt) * 10;
        #pragma unroll
        for (int k = 0; k < 10; ++k) { cs[base + k] = fs[k]; ci[base + k] = fi[k]; }
    }
}

// ---------------------------------------------------------------------------
// merge_rescore2: stream 10000 cands -> per-thread top-16 (regs) -> LDS 4096
// -> global top-16 -> fp64 rescore -> final top-10 + gather.
// ---------------------------------------------------------------------------
__global__ __launch_bounds__(256) void merge_rescore2_k(
    const float* __restrict__ cs, const int* __restrict__ ci,
    const float* __restrict__ P, const float* __restrict__ ANS,
    const double* __restrict__ invn64, const float* __restrict__ mask,
    float* __restrict__ out)
{
    __shared__ float  ls[4096];
    __shared__ int    li[4096];
    __shared__ float  rrs[4];
    __shared__ int    rri[4], rrp[4];
    __shared__ int    topi_s[16];
    __shared__ double tops_s[16];
    __shared__ int    fin_s[10];
    int row = blockIdx.x, tid = threadIdx.x;

    float s16[16]; int i16[16];
    #pragma unroll
    for (int q = 0; q < 16; ++q) { s16[q] = -INFINITY; i16[q] = 0x7fffffff; }
    const float* csr = cs + (size_t)row * CAND2;
    const int*   cir = ci + (size_t)row * CAND2;
    for (int j = tid; j < CAND2; j += 256)
        ins16(s16, i16, csr[j], cir[j]);
    #pragma unroll
    for (int q = 0; q < 16; ++q) { ls[tid * 16 + q] = s16[q]; li[tid * 16 + q] = i16[q]; }
    __syncthreads();

    for (int it = 0; it < 16; ++it) {
        float bsv = -INFINITY; int bi = 0x7fffffff, bp = -1;
        for (int j = tid; j < 4096; j += 256) {
            float s = ls[j];
            if (s > bsv || (s == bsv && li[j] < bi)) { bsv = s; bi = li[j]; bp = j; }
        }
        #pragma unroll
        for (int o = 32; o; o >>= 1) {
            float os = __shfl_down(bsv, o);
            int oi = __shfl_down(bi, o);
            int op = __shfl_down(bp, o);
            if (os > bsv || (os == bsv && oi < bi)) { bsv = os; bi = oi; bp = op; }
        }
        if ((tid & 63) == 0) { int w = tid >> 6; rrs[w] = bsv; rri[w] = bi; rrp[w] = bp; }
        __syncthreads();
        if (tid == 0) {
            for (int w = 1; w < 4; ++w)
                if (rrs[w] > bsv || (rrs[w] == bsv && rri[w] < bi)) {
                    bsv = rrs[w]; bi = rri[w]; bp = rrp[w];
                }
            topi_s[it] = bi;
            ls[bp] = -INFINITY;
        }
        __syncthreads();
    }

    // fp64 rescore: 16 threads per candidate
    int c = tid >> 4, part = tid & 15;
    int aidx = topi_s[c];
    const float4* p4 = (const float4*)(P + (size_t)row * DIM);
    const float4* a4 = (const float4*)(ANS + (size_t)aidx * DIM);
    double sum = 0.0;
    #pragma unroll
    for (int i = 0; i < 12; ++i) {
        float4 pv = p4[part * 12 + i];
        float4 av = a4[part * 12 + i];
        sum += (double)pv.x * av.x + (double)pv.y * av.y
             + (double)pv.z * av.z + (double)pv.w * av.w;
    }
    #pragma unroll
    for (int o = 8; o; o >>= 1) sum += __shfl_down(sum, o, 16);
    if (part == 0) {
        float m = mask[(size_t)row * NANS + aidx];
        tops_s[c] = sum * invn64[aidx] * (double)m;
    }
    __syncthreads();

    if (tid == 0) {
        unsigned used = 0;
        for (int k = 0; k < 10; ++k) {
            int bj = -1;
            for (int j = 0; j < 16; ++j) {
                if (used & (1u << j)) continue;
                if (bj < 0 || tops_s[j] > tops_s[bj] ||
                    (tops_s[j] == tops_s[bj] && topi_s[j] < topi_s[bj])) bj = j;
            }
            used |= 1u << bj;
            out[(size_t)row * 10 + k] = (float)tops_s[bj];
            out[10240 + (size_t)row * 10 + k] = (float)topi_s[bj];
            fin_s[k] = topi_s[bj];
        }
    }
    __syncthreads();

    for (int k = 0; k < 10; ++k) {
        int id = fin_s[k];
        const float* arow = ANS + (size_t)id * DIM;
        float* orow = out + 20480 + ((size_t)(row * 10 + k)) * DIM;
        for (int d = tid; d < DIM; d += 256) orow[d] = arow[d];
    }
}

// ---------------------------------------------------------------------------
extern "C" void kernel_launch(void* const* d_in, const int* in_sizes, int n_in,
                              void* d_out, int out_size, void* d_ws, size_t ws_size,
                              hipStream_t stream)
{
    (void)in_sizes; (void)n_in; (void)out_size;
    const float* visual = (const float*)d_in[0];
    const float* mask   = (const float*)d_in[2];
    const float* ans    = (const float*)d_in[3];
    const float* wv = (const float*)d_in[8];
    const float* bv = (const float*)d_in[9];
    const float* wo = (const float*)d_in[10];
    const float* bo = (const float*)d_in[11];
    const float* fw = (const float*)d_in[12];
    const float* fb = (const float*)d_in[13];
    const float* lg = (const float*)d_in[14];
    const float* lb = (const float*)d_in[15];
    const float* sw = (const float*)d_in[16];
    const float* sb = (const float*)d_in[17];
    float* out = (float*)d_out;

    // ---- workspace: persistent first, transient upstream + AB share tail ----
    char* w = (char*)d_ws;
    float*    P        = (float*)w;    w += (size_t)BATCH * DIM * 4;        // 3.1 MB
    short*    Pb       = (short*)w;    w += (size_t)BATCH * DIM * 2;        // 1.6 MB
    double*   invn64   = (double*)w;   w += (size_t)NANS * 8;               // 1.0 MB
    float*    cs       = (float*)w;    w += (size_t)BATCH * CAND2 * 4;      // 41 MB
    int*      ci       = (int*)w;      w += (size_t)BATCH * CAND2 * 4;      // 41 MB
    unsigned* bits     = (unsigned*)w; w += (size_t)BATCH * NWORDS * 4;     // 16.4 MB
    char*     tail     = w;
    float*    fused_in = (float*)tail;
    float*    v        = fused_in + (size_t)BATCH * 1536;
    float*    h        = v + (size_t)BATCH * DIM;
    short*    AB       = (short*)tail; // aliases upstream transients after death

    size_t used = (size_t)(tail - (char*)d_ws);
    size_t atile_bytes = (size_t)256 * DIM * 2;                // 393216 (256-row units)
    size_t avail = (ws_size > used) ? (ws_size - used) : atile_bytes;
    int CA = (int)(avail / atile_bytes);
    if (CA < 1) CA = 1;
    if (CA > 500) CA = 500;
    int nch = (500 + CA - 1) / CA;

    copy_visual_k<<<512, 256, 0, stream>>>(visual, fused_in);
    gemm_bias_k<<<dim3(16, 12), 256, 0, stream>>>(visual, DIM, wv, bv, v, DIM, DIM);
    gemm_bias_k<<<dim3(16, 12), 256, 0, stream>>>(v, DIM, wo, bo, fused_in + DIM, 1536, DIM);
    gemm_bias_k<<<dim3(16, 12), 256, 0, stream>>>(fused_in, 1536, fw, fb, h, DIM, 1536);
    ln_gelu_k<<<BATCH, 256, 0, stream>>>(h, lg, lb);
    gemm_bias_k<<<dim3(16, 12), 256, 0, stream>>>(h, DIM, sw, sb, P, DIM, DIM);
    l2norm_bf_k<<<BATCH, 256, 0, stream>>>(P, Pb);
    prep_mask_k<<<BATCH, 256, 0, stream>>>(mask, bits);
    // ---- upstream transients dead from here; AB may reuse them ----

    for (int ch = 0; ch < nch; ++ch) {
        int atile0 = ch * CA;
        int catiles = 500 - atile0; if (catiles > CA) catiles = CA;
        int nrows = catiles * 256;
        int nt128 = catiles * 2;
        prep_ans_k<<<(nrows + 3) / 4, 256, 0, stream>>>(ans, atile0 * 256, nrows,
                                                        invn64, AB);
        big4_k<<<nt128 * 8, 256, 0, stream>>>(Pb, AB, bits, cs, ci,
                                              atile0 * 2, nt128);
    }

    merge_rescore2_k<<<BATCH, 256, 0, stream>>>(cs, ci, P, ans, invn64, mask, out);
}

// Round 10
// 1923.448 us; speedup vs baseline: 2.2561x; 2.2561x over previous
//
#include <hip/hip_runtime.h>
#include <math.h>

#define DIM    768
#define BATCH  1024
#define NANS   128000
#define NT128  1000             // 128-answer shortlist tiles
#define NWORDS 4000             // mask bit-words per batch row (128000/32)

typedef short  bf16x8 __attribute__((ext_vector_type(8)));
typedef float  f32x4  __attribute__((ext_vector_type(4)));

__device__ __forceinline__ short f2bf(float x)
{
    unsigned u = __builtin_bit_cast(unsigned, x);
    u += 0x7fffu + ((u >> 16) & 1u);          // RNE (no NaN inputs here)
    return (short)(u >> 16);
}

__device__ __forceinline__ void gload16(const void* g, void* l)
{
    __builtin_amdgcn_global_load_lds(
        (const __attribute__((address_space(1))) void*)g,
        (__attribute__((address_space(3))) void*)l, 16, 0, 0);
}

// sorted-descending top-10 insertion (static indices only)
__device__ __forceinline__ void ins10(float (&s)[10], int (&ix)[10], float v, int vi)
{
    if (v > s[9] || (v == s[9] && vi < ix[9])) {
        s[9] = v; ix[9] = vi;
        #pragma unroll
        for (int q = 9; q > 0; --q) {
            bool sw = (s[q] > s[q-1]) || (s[q] == s[q-1] && ix[q] < ix[q-1]);
            float ts = s[q-1]; int ti = ix[q-1];
            s[q-1] = sw ? s[q] : s[q-1]; ix[q-1] = sw ? ix[q] : ix[q-1];
            s[q]   = sw ? ts   : s[q];   ix[q]   = sw ? ti   : ix[q];
        }
    }
}

__device__ __forceinline__ void ins16(float (&s)[16], int (&ix)[16], float v, int vi)
{
    if (v > s[15] || (v == s[15] && vi < ix[15])) {
        s[15] = v; ix[15] = vi;
        #pragma unroll
        for (int q = 15; q > 0; --q) {
            bool sw = (s[q] > s[q-1]) || (s[q] == s[q-1] && ix[q] < ix[q-1]);
            float ts = s[q-1]; int ti = ix[q-1];
            s[q-1] = sw ? s[q] : s[q-1]; ix[q-1] = sw ? ix[q] : ix[q-1];
            s[q]   = sw ? ts   : s[q];   ix[q]   = sw ? ti   : ix[q];
        }
    }
}

// ---------------------------------------------------------------------------
// Upstream GEMM: C[M,N] = A[M,K] @ W[N,K]^T + bias   (fp32)
// ---------------------------------------------------------------------------
__global__ __launch_bounds__(256, 2) void gemm_bias_k(
    const float* __restrict__ A, int lda,
    const float* __restrict__ W,
    const float* __restrict__ bias,
    float* __restrict__ C, int ldc, int K)
{
    __shared__ float as[32][68];
    __shared__ float bs[32][68];
    int m0 = blockIdx.x * 64, n0 = blockIdx.y * 64;
    int tid = threadIdx.x;
    int tm = tid & 15, tn = tid >> 4;
    int sr = tid >> 3, skq = tid & 7;
    float acc[4][4] = {};
    for (int k0 = 0; k0 < K; k0 += 32) {
        __syncthreads();
        #pragma unroll
        for (int p = 0; p < 2; ++p) {
            int r = sr + 32 * p;
            float4 av = *(const float4*)&A[(size_t)(m0 + r) * lda + k0 + skq * 4];
            as[skq*4+0][r] = av.x; as[skq*4+1][r] = av.y;
            as[skq*4+2][r] = av.z; as[skq*4+3][r] = av.w;
            float4 wv = *(const float4*)&W[(size_t)(n0 + r) * K + k0 + skq * 4];
            bs[skq*4+0][r] = wv.x; bs[skq*4+1][r] = wv.y;
            bs[skq*4+2][r] = wv.z; bs[skq*4+3][r] = wv.w;
        }
        __syncthreads();
        #pragma unroll 8
        for (int k = 0; k < 32; ++k) {
            float a4[4], b4[4];
            *(float4*)a4 = *(const float4*)&as[k][tm*4];
            *(float4*)b4 = *(const float4*)&bs[k][tn*4];
            #pragma unroll
            for (int i = 0; i < 4; ++i)
                #pragma unroll
                for (int j = 0; j < 4; ++j)
                    acc[i][j] = fmaf(a4[i], b4[j], acc[i][j]);
        }
    }
    float4 bv4 = *(const float4*)&bias[n0 + tn*4];
    #pragma unroll
    for (int i = 0; i < 4; ++i) {
        float4 c4;
        c4.x = acc[i][0] + bv4.x; c4.y = acc[i][1] + bv4.y;
        c4.z = acc[i][2] + bv4.z; c4.w = acc[i][3] + bv4.w;
        *(float4*)&C[(size_t)(m0 + tm*4 + i) * ldc + n0 + tn*4] = c4;
    }
}

// ---------------------------------------------------------------------------
__global__ void copy_visual_k(const float* __restrict__ src, float* __restrict__ dst)
{
    int idx = blockIdx.x * 256 + threadIdx.x;          // float4 index
    const int total = BATCH * (DIM / 4);
    for (; idx < total; idx += 512 * 256) {
        int b = idx / (DIM / 4), c = idx % (DIM / 4);
        ((float4*)dst)[(size_t)b * (1536 / 4) + c] = ((const float4*)src)[idx];
    }
}

// ---------------------------------------------------------------------------
__device__ __forceinline__ float block_sum(float v, float* red)
{
    #pragma unroll
    for (int o = 32; o; o >>= 1) v += __shfl_down(v, o);
    if ((threadIdx.x & 63) == 0) red[threadIdx.x >> 6] = v;
    __syncthreads();
    float r = red[0] + red[1] + red[2] + red[3];
    __syncthreads();
    return r;
}

__global__ __launch_bounds__(256) void ln_gelu_k(float* __restrict__ H,
        const float* __restrict__ g, const float* __restrict__ b)
{
    __shared__ float red[4];
    int row = blockIdx.x, tid = threadIdx.x;
    float* hr = H + (size_t)row * DIM;
    float v0 = hr[tid], v1 = hr[tid + 256], v2 = hr[tid + 512];
    float mu = block_sum(v0 + v1 + v2, red) * (1.0f / 768.0f);
    float d0 = v0 - mu, d1 = v1 - mu, d2 = v2 - mu;
    float var = block_sum(d0*d0 + d1*d1 + d2*d2, red) * (1.0f / 768.0f);
    float rinv = 1.0f / sqrtf(var + 1e-5f);
    #pragma unroll
    for (int q = 0; q < 3; ++q) {
        int d = tid + 256 * q;
        float dd = (q == 0 ? d0 : (q == 1 ? d1 : d2));
        float y = dd * rinv * g[d] + b[d];
        hr[d] = 0.5f * y * (1.0f + erff(y * 0.70710678118654752f));
    }
}

// l2-normalize P in place, also emit bf16 copy
__global__ __launch_bounds__(256) void l2norm_bf_k(float* __restrict__ P,
        short* __restrict__ Pb)
{
    __shared__ float red[4];
    int row = blockIdx.x, tid = threadIdx.x;
    float* pr = P + (size_t)row * DIM;
    short* pb = Pb + (size_t)row * DIM;
    float v0 = pr[tid], v1 = pr[tid + 256], v2 = pr[tid + 512];
    float ss = block_sum(v0*v0 + v1*v1 + v2*v2, red);
    float inv = 1.0f / fmaxf(sqrtf(ss), 1e-12f);
    v0 *= inv; v1 *= inv; v2 *= inv;
    pr[tid] = v0; pr[tid + 256] = v1; pr[tid + 512] = v2;
    pb[tid] = f2bf(v0); pb[tid + 256] = f2bf(v1); pb[tid + 512] = f2bf(v2);
}

// ---------------------------------------------------------------------------
// prep_ans: fp64 row norm -> inv64[row]; unit-normalized bf16 rows into AB.
// ---------------------------------------------------------------------------
__global__ __launch_bounds__(256) void prep_ans_k(
    const float* __restrict__ ANS, int row0, int nrows,
    double* __restrict__ inv64, short* __restrict__ AB)
{
    int r = blockIdx.x * 4 + (threadIdx.x >> 6);
    if (r >= nrows) return;
    int row = row0 + r;
    int lane = threadIdx.x & 63;
    const float4* a4 = (const float4*)(ANS + (size_t)row * DIM);
    float4 x0 = a4[lane], x1 = a4[lane + 64], x2 = a4[lane + 128];
    double ss = (double)x0.x*x0.x + (double)x0.y*x0.y + (double)x0.z*x0.z + (double)x0.w*x0.w
              + (double)x1.x*x1.x + (double)x1.y*x1.y + (double)x1.z*x1.z + (double)x1.w*x1.w
              + (double)x2.x*x2.x + (double)x2.y*x2.y + (double)x2.z*x2.z + (double)x2.w*x2.w;
    #pragma unroll
    for (int o = 32; o; o >>= 1) ss += __shfl_xor(ss, o);
    double inv = 1.0 / fmax(sqrt(ss), 1e-12);
    if (lane == 0) inv64[row] = inv;
    float invf = (float)inv;
    short* ob = AB + (size_t)r * DIM;
    ushort4 o0, o1, o2;
    o0.x = (unsigned short)f2bf(x0.x*invf); o0.y = (unsigned short)f2bf(x0.y*invf);
    o0.z = (unsigned short)f2bf(x0.z*invf); o0.w = (unsigned short)f2bf(x0.w*invf);
    o1.x = (unsigned short)f2bf(x1.x*invf); o1.y = (unsigned short)f2bf(x1.y*invf);
    o1.z = (unsigned short)f2bf(x1.z*invf); o1.w = (unsigned short)f2bf(x1.w*invf);
    o2.x = (unsigned short)f2bf(x2.x*invf); o2.y = (unsigned short)f2bf(x2.y*invf);
    o2.z = (unsigned short)f2bf(x2.z*invf); o2.w = (unsigned short)f2bf(x2.w*invf);
    *(ushort4*)&ob[lane * 4]           = o0;
    *(ushort4*)&ob[(lane + 64) * 4]    = o1;
    *(ushort4*)&ob[(lane + 128) * 4]   = o2;
}

// ---------------------------------------------------------------------------
// prep_maskT: float mask [1024][128000] -> TRANSPOSED bits [4000][1024]
// grid (4, 100): block covers 256 rows x 40 words. Coalesced bitsT writes.
// ---------------------------------------------------------------------------
__global__ __launch_bounds__(256, 4) void prep_maskT_k(
    const float* __restrict__ mask, unsigned* __restrict__ bitsT)
{
    int r = blockIdx.x * 256 + threadIdx.x;
    int w0 = blockIdx.y * 40;
    const float* mr = mask + (size_t)r * NANS;
    for (int w = w0; w < w0 + 40; ++w) {
        const float4* p = (const float4*)(mr + w * 32);
        unsigned b = 0;
        #pragma unroll
        for (int q = 0; q < 8; ++q) {
            float4 v = p[q];
            b |= ((unsigned)(v.x != 0.f)) << (q*4+0);
            b |= ((unsigned)(v.y != 0.f)) << (q*4+1);
            b |= ((unsigned)(v.z != 0.f)) << (q*4+2);
            b |= ((unsigned)(v.w != 0.f)) << (q*4+3);
        }
        bitsT[(size_t)w * BATCH + r] = b;
    }
}

// ---------------------------------------------------------------------------
// gemmA_k: PURE m97-structure MFMA GEMM -> raw scores to global.
// 256 thr / 4 waves; tile 128 answers x 128 batch; BK=32; 24 K-steps;
// global_load_lds(16) staging, linear LDS [row][32]; NO mask, NO topk.
// SC layout: [chunk_answer][1024 batch] fp32, coalesced float4 stores.
// ---------------------------------------------------------------------------
__global__ __launch_bounds__(256, 2) void gemmA_k(
    const short* __restrict__ Pb,       // [1024][768] unit-norm bf16
    const short* __restrict__ AB,       // chunk rows, unit-norm bf16
    float* __restrict__ SC,             // [nt128*128][1024]
    int nt128)
{
    __shared__ __align__(16) char smem[33792];
    short* a_sh = (short*)smem;                 // [128][32] = 8192 B
    short* b_sh = (short*)(smem + 8192);        // [128][32] = 8192 B
    float* scl  = (float*)smem;                 // reuse after loop: [64][132]

    // XCD swizzle: blocks on one XCD share an answer tile (nwg % 8 == 0)
    int bid = blockIdx.x;
    int v = (bid & 7) * nt128 + (bid >> 3);
    int at = v >> 3, bt = v & 7;
    int a0l = at * 128, b0 = bt * 128;

    int t = threadIdx.x;
    int lane = t & 63, wid = t >> 6;
    int wm = wid & 1, wn = wid >> 1;            // 2x2 wave grid of 64x64
    int lr = lane & 15, lg = lane >> 4;

    const char* gA0 = (const char*)(AB + (size_t)(a0l + (t >> 2)) * DIM + (t & 3) * 8);
    const char* gA1 = (const char*)(AB + (size_t)(a0l + 64 + (t >> 2)) * DIM + (t & 3) * 8);
    const char* gB0 = (const char*)(Pb + (size_t)(b0 + (t >> 2)) * DIM + (t & 3) * 8);
    const char* gB1 = (const char*)(Pb + (size_t)(b0 + 64 + (t >> 2)) * DIM + (t & 3) * 8);
    char* la0 = (char*)a_sh + t * 16;
    char* la1 = (char*)a_sh + 4096 + t * 16;
    char* lb0 = (char*)b_sh + t * 16;
    char* lb1 = (char*)b_sh + 4096 + t * 16;

    f32x4 acc[4][4];
    #pragma unroll
    for (int i = 0; i < 4; ++i)
        #pragma unroll
        for (int j = 0; j < 4; ++j)
            acc[i][j] = (f32x4){0.f, 0.f, 0.f, 0.f};

    for (int kt = 0; kt < 24; ++kt) {
        gload16(gA0, la0);
        gload16(gA1, la1);
        gload16(gB0, lb0);
        gload16(gB1, lb1);
        gA0 += 64; gA1 += 64; gB0 += 64; gB1 += 64;
        __syncthreads();                        // drain vmcnt + barrier
        bf16x8 af[4], bg[4];
        #pragma unroll
        for (int mt = 0; mt < 4; ++mt)
            af[mt] = *(const bf16x8*)(a_sh + (wm*64 + mt*16 + lr) * 32 + lg*8);
        #pragma unroll
        for (int nt = 0; nt < 4; ++nt)
            bg[nt] = *(const bf16x8*)(b_sh + (wn*64 + nt*16 + lr) * 32 + lg*8);
        #pragma unroll
        for (int mt = 0; mt < 4; ++mt)
            #pragma unroll
            for (int nt = 0; nt < 4; ++nt)
                acc[mt][nt] = __builtin_amdgcn_mfma_f32_16x16x32_bf16(
                    af[mt], bg[nt], acc[mt][nt], 0, 0, 0);
        __syncthreads();                        // reads done before next stage
    }

    // ---- epilogue: dump 64-answer chunks via LDS, coalesced f4 stores ----
    int rloc = t >> 5, c4 = t & 31;
    for (int c = 0; c < 2; ++c) {
        __syncthreads();
        if (wm == c) {
            #pragma unroll
            for (int nt = 0; nt < 4; ++nt) {
                int lcol = wn * 64 + nt * 16 + lr;
                #pragma unroll
                for (int mt = 0; mt < 4; ++mt) {
                    int lrow = mt * 16 + lg * 4;
                    scl[(lrow + 0) * 132 + lcol] = acc[mt][nt][0];
                    scl[(lrow + 1) * 132 + lcol] = acc[mt][nt][1];
                    scl[(lrow + 2) * 132 + lcol] = acc[mt][nt][2];
                    scl[(lrow + 3) * 132 + lcol] = acc[mt][nt][3];
                }
            }
        }
        __syncthreads();
        #pragma unroll
        for (int i = 0; i < 8; ++i) {
            int row = i * 8 + rloc;
            float4 val = *(const float4*)&scl[row * 132 + c4 * 4];
            *(float4*)&SC[(size_t)(a0l + c * 64 + row) * BATCH + b0 + c4 * 4] = val;
        }
    }
}

// ---------------------------------------------------------------------------
// selB_k: stream scores + bitmask -> per-(row, 128-tile) top-10 shortlist.
// Thread = one batch row; block = 256 rows x 2 tiles. All loads coalesced.
// Shortlist layout [tile][row][10] for coalesced writes.
// ---------------------------------------------------------------------------
__global__ __launch_bounds__(256, 4) void selB_k(
    const float* __restrict__ SC,       // [nt128*128][1024] chunk-local
    const unsigned* __restrict__ bitsT, // [4000][1024]
    float* __restrict__ cs2, int* __restrict__ ci2,  // [1000][1024][10]
    int t128_0, int nt128)
{
    int r = blockIdx.x * 256 + threadIdx.x;     // batch row
    for (int s = 0; s < 2; ++s) {
        int tl = blockIdx.y * 2 + s;            // chunk-local tile
        if (tl >= nt128) break;
        int gt = t128_0 + tl;                   // global tile
        float s10[10]; int i10[10];
        #pragma unroll
        for (int q = 0; q < 10; ++q) { s10[q] = -INFINITY; i10[q] = 0x7fffffff; }
        const float* sc = SC + (size_t)tl * 128 * BATCH + r;
        for (int c = 0; c < 4; ++c) {
            unsigned wv = bitsT[(size_t)(gt * 4 + c) * BATCH + r];
            const float* scc = sc + (size_t)c * 32 * BATCH;
            for (int i = 0; i < 32; ++i) {
                float vsc = scc[(size_t)i * BATCH];
                vsc = ((wv >> i) & 1u) ? vsc : 0.0f;
                ins10(s10, i10, vsc, gt * 128 + c * 32 + i);
            }
        }
        size_t base = ((size_t)gt * BATCH + r) * 10;
        #pragma unroll
        for (int k = 0; k < 10; ++k) { cs2[base + k] = s10[k]; ci2[base + k] = i10[k]; }
    }
}

// ---------------------------------------------------------------------------
// merge_rescore2: stream 10000 cands -> per-thread top-16 (regs) -> LDS 4096
// -> global top-16 -> fp64 rescore -> final top-10 + gather.
// ---------------------------------------------------------------------------
__global__ __launch_bounds__(256) void merge_rescore2_k(
    const float* __restrict__ cs2, const int* __restrict__ ci2,
    const float* __restrict__ P, const float* __restrict__ ANS,
    const double* __restrict__ invn64, const float* __restrict__ mask,
    float* __restrict__ out)
{
    __shared__ float  ls[4096];
    __shared__ int    li[4096];
    __shared__ float  rrs[4];
    __shared__ int    rri[4], rrp[4];
    __shared__ int    topi_s[16];
    __shared__ double tops_s[16];
    __shared__ int    fin_s[10];
    int row = blockIdx.x, tid = threadIdx.x;

    float s16[16]; int i16[16];
    #pragma unroll
    for (int q = 0; q < 16; ++q) { s16[q] = -INFINITY; i16[q] = 0x7fffffff; }
    for (int gt = tid; gt < NT128; gt += 256) {
        size_t base = ((size_t)gt * BATCH + row) * 10;
        #pragma unroll
        for (int k = 0; k < 10; ++k)
            ins16(s16, i16, cs2[base + k], ci2[base + k]);
    }
    #pragma unroll
    for (int q = 0; q < 16; ++q) { ls[tid * 16 + q] = s16[q]; li[tid * 16 + q] = i16[q]; }
    __syncthreads();

    for (int it = 0; it < 16; ++it) {
        float bsv = -INFINITY; int bi = 0x7fffffff, bp = -1;
        for (int j = tid; j < 4096; j += 256) {
            float s = ls[j];
            if (s > bsv || (s == bsv && li[j] < bi)) { bsv = s; bi = li[j]; bp = j; }
        }
        #pragma unroll
        for (int o = 32; o; o >>= 1) {
            float os = __shfl_down(bsv, o);
            int oi = __shfl_down(bi, o);
            int op = __shfl_down(bp, o);
            if (os > bsv || (os == bsv && oi < bi)) { bsv = os; bi = oi; bp = op; }
        }
        if ((tid & 63) == 0) { int w = tid >> 6; rrs[w] = bsv; rri[w] = bi; rrp[w] = bp; }
        __syncthreads();
        if (tid == 0) {
            for (int w = 1; w < 4; ++w)
                if (rrs[w] > bsv || (rrs[w] == bsv && rri[w] < bi)) {
                    bsv = rrs[w]; bi = rri[w]; bp = rrp[w];
                }
            topi_s[it] = bi;
            ls[bp] = -INFINITY;
        }
        __syncthreads();
    }

    // fp64 rescore: 16 threads per candidate
    int c = tid >> 4, part = tid & 15;
    int aidx = topi_s[c];
    const float4* p4 = (const float4*)(P + (size_t)row * DIM);
    const float4* a4 = (const float4*)(ANS + (size_t)aidx * DIM);
    double sum = 0.0;
    #pragma unroll
    for (int i = 0; i < 12; ++i) {
        float4 pv = p4[part * 12 + i];
        float4 av = a4[part * 12 + i];
        sum += (double)pv.x * av.x + (double)pv.y * av.y
             + (double)pv.z * av.z + (double)pv.w * av.w;
    }
    #pragma unroll
    for (int o = 8; o; o >>= 1) sum += __shfl_down(sum, o, 16);
    if (part == 0) {
        float m = mask[(size_t)row * NANS + aidx];
        tops_s[c] = sum * invn64[aidx] * (double)m;
    }
    __syncthreads();

    if (tid == 0) {
        unsigned used = 0;
        for (int k = 0; k < 10; ++k) {
            int bj = -1;
            for (int j = 0; j < 16; ++j) {
                if (used & (1u << j)) continue;
                if (bj < 0 || tops_s[j] > tops_s[bj] ||
                    (tops_s[j] == tops_s[bj] && topi_s[j] < topi_s[bj])) bj = j;
            }
            used |= 1u << bj;
            out[(size_t)row * 10 + k] = (float)tops_s[bj];
            out[10240 + (size_t)row * 10 + k] = (float)topi_s[bj];
            fin_s[k] = topi_s[bj];
        }
    }
    __syncthreads();

    for (int k = 0; k < 10; ++k) {
        int id = fin_s[k];
        const float* arow = ANS + (size_t)id * DIM;
        float* orow = out + 20480 + ((size_t)(row * 10 + k)) * DIM;
        for (int d = tid; d < DIM; d += 256) orow[d] = arow[d];
    }
}

// ---------------------------------------------------------------------------
extern "C" void kernel_launch(void* const* d_in, const int* in_sizes, int n_in,
                              void* d_out, int out_size, void* d_ws, size_t ws_size,
                              hipStream_t stream)
{
    (void)in_sizes; (void)n_in; (void)out_size;
    const float* visual = (const float*)d_in[0];
    const float* mask   = (const float*)d_in[2];
    const float* ans    = (const float*)d_in[3];
    const float* wv = (const float*)d_in[8];
    const float* bv = (const float*)d_in[9];
    const float* wo = (const float*)d_in[10];
    const float* bo = (const float*)d_in[11];
    const float* fw = (const float*)d_in[12];
    const float* fb = (const float*)d_in[13];
    const float* lg = (const float*)d_in[14];
    const float* lb = (const float*)d_in[15];
    const float* sw = (const float*)d_in[16];
    const float* sb = (const float*)d_in[17];
    float* out = (float*)d_out;

    // ---- workspace: persistent first; transient upstream + AB/SC share tail ----
    char* w = (char*)d_ws;
    float*    P      = (float*)w;    w += (size_t)BATCH * DIM * 4;          // 3.1 MB
    short*    Pb     = (short*)w;    w += (size_t)BATCH * DIM * 2;          // 1.6 MB
    double*   invn64 = (double*)w;   w += (size_t)NANS * 8;                 // 1.0 MB
    float*    cs2    = (float*)w;    w += (size_t)NT128 * BATCH * 10 * 4;   // 41 MB
    int*      ci2    = (int*)w;      w += (size_t)NT128 * BATCH * 10 * 4;   // 41 MB
    unsigned* bitsT  = (unsigned*)w; w += (size_t)NWORDS * BATCH * 4;       // 16.4 MB
    char*     tail   = w;
    float*    fused_in = (float*)tail;
    float*    v        = fused_in + (size_t)BATCH * 1536;
    float*    h        = v + (size_t)BATCH * DIM;

    // per-128-tile chunk bytes: AB (128*768*2) + SC (128*1024*4)
    size_t ab_t = (size_t)128 * DIM * 2;        // 196608
    size_t sc_t = (size_t)128 * BATCH * 4;      // 524288
    size_t used = (size_t)(tail - (char*)d_ws);
    size_t avail = (ws_size > used) ? (ws_size - used) : 2 * (ab_t + sc_t);
    int CT = (int)(avail / (ab_t + sc_t));      // tiles per chunk
    CT &= ~1;                                   // even
    if (CT < 2) CT = 2;
    if (CT > NT128) CT = NT128;
    int nch = (NT128 + CT - 1) / CT;

    copy_visual_k<<<512, 256, 0, stream>>>(visual, fused_in);
    gemm_bias_k<<<dim3(16, 12), 256, 0, stream>>>(visual, DIM, wv, bv, v, DIM, DIM);
    gemm_bias_k<<<dim3(16, 12), 256, 0, stream>>>(v, DIM, wo, bo, fused_in + DIM, 1536, DIM);
    gemm_bias_k<<<dim3(16, 12), 256, 0, stream>>>(fused_in, 1536, fw, fb, h, DIM, 1536);
    ln_gelu_k<<<BATCH, 256, 0, stream>>>(h, lg, lb);
    gemm_bias_k<<<dim3(16, 12), 256, 0, stream>>>(h, DIM, sw, sb, P, DIM, DIM);
    l2norm_bf_k<<<BATCH, 256, 0, stream>>>(P, Pb);
    prep_maskT_k<<<dim3(4, 100), 256, 0, stream>>>(mask, bitsT);
    // ---- upstream transients dead from here; AB/SC reuse the tail ----
    short* AB = (short*)tail;
    float* SC = (float*)(tail + (size_t)CT * ab_t);

    for (int ch = 0; ch < nch; ++ch) {
        int t0 = ch * CT;
        int n = NT128 - t0; if (n > CT) n = CT;
        int nrows = n * 128;
        prep_ans_k<<<(nrows + 3) / 4, 256, 0, stream>>>(ans, t0 * 128, nrows,
                                                        invn64, AB);
        gemmA_k<<<n * 8, 256, 0, stream>>>(Pb, AB, SC, n);
        selB_k<<<dim3(4, (n + 1) / 2), 256, 0, stream>>>(SC, bitsT, cs2, ci2, t0, n);
    }

    merge_rescore2_k<<<BATCH, 256, 0, stream>>>(cs2, ci2, P, ans, invn64, mask, out);
}

// Round 11
// 1717.625 us; speedup vs baseline: 2.5265x; 1.1198x over previous
//
#include <hip/hip_runtime.h>
#include <math.h>

#define DIM    768
#define BATCH  1024
#define NANS   128000
#define NT128  1000             // 128-answer shortlist tiles
#define NWORDS 4000             // mask bit-words per batch row (128000/32)

typedef short  bf16x8 __attribute__((ext_vector_type(8)));
typedef float  f32x4  __attribute__((ext_vector_type(4)));

__device__ __forceinline__ short f2bf(float x)
{
    unsigned u = __builtin_bit_cast(unsigned, x);
    u += 0x7fffu + ((u >> 16) & 1u);          // RNE (no NaN inputs here)
    return (short)(u >> 16);
}

__device__ __forceinline__ void gload16(const void* g, void* l)
{
    __builtin_amdgcn_global_load_lds(
        (const __attribute__((address_space(1))) void*)g,
        (__attribute__((address_space(3))) void*)l, 16, 0, 0);
}

// ---------------------------------------------------------------------------
// Register-resident top-K: NAMED scalar slots (no arrays -> no scratch).
// Trickle-down insert: v swaps into the first slot it beats; rest shift down.
// Tie rule: equal score -> lower index ranks higher (matches np/jax top_k).
// ---------------------------------------------------------------------------
struct Top10 {
    float s0,s1,s2,s3,s4,s5,s6,s7,s8,s9;
    int   i0,i1,i2,i3,i4,i5,i6,i7,i8,i9;
};
__device__ __forceinline__ void t10_init(Top10& t)
{
    t.s0=t.s1=t.s2=t.s3=t.s4=t.s5=t.s6=t.s7=t.s8=t.s9=-INFINITY;
    t.i0=t.i1=t.i2=t.i3=t.i4=t.i5=t.i6=t.i7=t.i8=t.i9=0x7fffffff;
}
__device__ __forceinline__ void t10_ins(Top10& t, float v, int vi)
{
#define T10_STEP(S,I) { bool g=(v>t.S)||(v==t.S&&vi<t.I); \
    float ts_=t.S; int ti_=t.I; \
    t.S=g?v:t.S; t.I=g?vi:t.I; v=g?ts_:v; vi=g?ti_:vi; }
    T10_STEP(s0,i0) T10_STEP(s1,i1) T10_STEP(s2,i2) T10_STEP(s3,i3)
    T10_STEP(s4,i4) T10_STEP(s5,i5) T10_STEP(s6,i6) T10_STEP(s7,i7)
    T10_STEP(s8,i8) T10_STEP(s9,i9)
#undef T10_STEP
}

struct Top16 {
    float s0,s1,s2,s3,s4,s5,s6,s7,s8,s9,s10,s11,s12,s13,s14,s15;
    int   i0,i1,i2,i3,i4,i5,i6,i7,i8,i9,i10,i11,i12,i13,i14,i15;
};
__device__ __forceinline__ void t16_init(Top16& t)
{
    t.s0=t.s1=t.s2=t.s3=t.s4=t.s5=t.s6=t.s7=-INFINITY;
    t.s8=t.s9=t.s10=t.s11=t.s12=t.s13=t.s14=t.s15=-INFINITY;
    t.i0=t.i1=t.i2=t.i3=t.i4=t.i5=t.i6=t.i7=0x7fffffff;
    t.i8=t.i9=t.i10=t.i11=t.i12=t.i13=t.i14=t.i15=0x7fffffff;
}
__device__ __forceinline__ void t16_ins(Top16& t, float v, int vi)
{
#define T16_STEP(S,I) { bool g=(v>t.S)||(v==t.S&&vi<t.I); \
    float ts_=t.S; int ti_=t.I; \
    t.S=g?v:t.S; t.I=g?vi:t.I; v=g?ts_:v; vi=g?ti_:vi; }
    T16_STEP(s0,i0)   T16_STEP(s1,i1)   T16_STEP(s2,i2)   T16_STEP(s3,i3)
    T16_STEP(s4,i4)   T16_STEP(s5,i5)   T16_STEP(s6,i6)   T16_STEP(s7,i7)
    T16_STEP(s8,i8)   T16_STEP(s9,i9)   T16_STEP(s10,i10) T16_STEP(s11,i11)
    T16_STEP(s12,i12) T16_STEP(s13,i13) T16_STEP(s14,i14) T16_STEP(s15,i15)
#undef T16_STEP
}

// ---------------------------------------------------------------------------
// Upstream GEMM: C[M,N] = A[M,K] @ W[N,K]^T + bias   (fp32)
// ---------------------------------------------------------------------------
__global__ __launch_bounds__(256, 2) void gemm_bias_k(
    const float* __restrict__ A, int lda,
    const float* __restrict__ W,
    const float* __restrict__ bias,
    float* __restrict__ C, int ldc, int K)
{
    __shared__ float as[32][68];
    __shared__ float bs[32][68];
    int m0 = blockIdx.x * 64, n0 = blockIdx.y * 64;
    int tid = threadIdx.x;
    int tm = tid & 15, tn = tid >> 4;
    int sr = tid >> 3, skq = tid & 7;
    float acc[4][4] = {};
    for (int k0 = 0; k0 < K; k0 += 32) {
        __syncthreads();
        #pragma unroll
        for (int p = 0; p < 2; ++p) {
            int r = sr + 32 * p;
            float4 av = *(const float4*)&A[(size_t)(m0 + r) * lda + k0 + skq * 4];
            as[skq*4+0][r] = av.x; as[skq*4+1][r] = av.y;
            as[skq*4+2][r] = av.z; as[skq*4+3][r] = av.w;
            float4 wv = *(const float4*)&W[(size_t)(n0 + r) * K + k0 + skq * 4];
            bs[skq*4+0][r] = wv.x; bs[skq*4+1][r] = wv.y;
            bs[skq*4+2][r] = wv.z; bs[skq*4+3][r] = wv.w;
        }
        __syncthreads();
        #pragma unroll 8
        for (int k = 0; k < 32; ++k) {
            float a4[4], b4[4];
            *(float4*)a4 = *(const float4*)&as[k][tm*4];
            *(float4*)b4 = *(const float4*)&bs[k][tn*4];
            #pragma unroll
            for (int i = 0; i < 4; ++i)
                #pragma unroll
                for (int j = 0; j < 4; ++j)
                    acc[i][j] = fmaf(a4[i], b4[j], acc[i][j]);
        }
    }
    float4 bv4 = *(const float4*)&bias[n0 + tn*4];
    #pragma unroll
    for (int i = 0; i < 4; ++i) {
        float4 c4;
        c4.x = acc[i][0] + bv4.x; c4.y = acc[i][1] + bv4.y;
        c4.z = acc[i][2] + bv4.z; c4.w = acc[i][3] + bv4.w;
        *(float4*)&C[(size_t)(m0 + tm*4 + i) * ldc + n0 + tn*4] = c4;
    }
}

// ---------------------------------------------------------------------------
__global__ void copy_visual_k(const float* __restrict__ src, float* __restrict__ dst)
{
    int idx = blockIdx.x * 256 + threadIdx.x;          // float4 index
    const int total = BATCH * (DIM / 4);
    for (; idx < total; idx += 512 * 256) {
        int b = idx / (DIM / 4), c = idx % (DIM / 4);
        ((float4*)dst)[(size_t)b * (1536 / 4) + c] = ((const float4*)src)[idx];
    }
}

// ---------------------------------------------------------------------------
__device__ __forceinline__ float block_sum(float v, float* red)
{
    #pragma unroll
    for (int o = 32; o; o >>= 1) v += __shfl_down(v, o);
    if ((threadIdx.x & 63) == 0) red[threadIdx.x >> 6] = v;
    __syncthreads();
    float r = red[0] + red[1] + red[2] + red[3];
    __syncthreads();
    return r;
}

__global__ __launch_bounds__(256) void ln_gelu_k(float* __restrict__ H,
        const float* __restrict__ g, const float* __restrict__ b)
{
    __shared__ float red[4];
    int row = blockIdx.x, tid = threadIdx.x;
    float* hr = H + (size_t)row * DIM;
    float v0 = hr[tid], v1 = hr[tid + 256], v2 = hr[tid + 512];
    float mu = block_sum(v0 + v1 + v2, red) * (1.0f / 768.0f);
    float d0 = v0 - mu, d1 = v1 - mu, d2 = v2 - mu;
    float var = block_sum(d0*d0 + d1*d1 + d2*d2, red) * (1.0f / 768.0f);
    float rinv = 1.0f / sqrtf(var + 1e-5f);
    #pragma unroll
    for (int q = 0; q < 3; ++q) {
        int d = tid + 256 * q;
        float dd = (q == 0 ? d0 : (q == 1 ? d1 : d2));
        float y = dd * rinv * g[d] + b[d];
        hr[d] = 0.5f * y * (1.0f + erff(y * 0.70710678118654752f));
    }
}

// l2-normalize P in place, also emit bf16 copy
__global__ __launch_bounds__(256) void l2norm_bf_k(float* __restrict__ P,
        short* __restrict__ Pb)
{
    __shared__ float red[4];
    int row = blockIdx.x, tid = threadIdx.x;
    float* pr = P + (size_t)row * DIM;
    short* pb = Pb + (size_t)row * DIM;
    float v0 = pr[tid], v1 = pr[tid + 256], v2 = pr[tid + 512];
    float ss = block_sum(v0*v0 + v1*v1 + v2*v2, red);
    float inv = 1.0f / fmaxf(sqrtf(ss), 1e-12f);
    v0 *= inv; v1 *= inv; v2 *= inv;
    pr[tid] = v0; pr[tid + 256] = v1; pr[tid + 512] = v2;
    pb[tid] = f2bf(v0); pb[tid + 256] = f2bf(v1); pb[tid + 512] = f2bf(v2);
}

// ---------------------------------------------------------------------------
// prep_ans: fp64 row norm -> inv64[row]; unit-normalized bf16 rows into AB.
// ---------------------------------------------------------------------------
__global__ __launch_bounds__(256) void prep_ans_k(
    const float* __restrict__ ANS, int row0, int nrows,
    double* __restrict__ inv64, short* __restrict__ AB)
{
    int r = blockIdx.x * 4 + (threadIdx.x >> 6);
    if (r >= nrows) return;
    int row = row0 + r;
    int lane = threadIdx.x & 63;
    const float4* a4 = (const float4*)(ANS + (size_t)row * DIM);
    float4 x0 = a4[lane], x1 = a4[lane + 64], x2 = a4[lane + 128];
    double ss = (double)x0.x*x0.x + (double)x0.y*x0.y + (double)x0.z*x0.z + (double)x0.w*x0.w
              + (double)x1.x*x1.x + (double)x1.y*x1.y + (double)x1.z*x1.z + (double)x1.w*x1.w
              + (double)x2.x*x2.x + (double)x2.y*x2.y + (double)x2.z*x2.z + (double)x2.w*x2.w;
    #pragma unroll
    for (int o = 32; o; o >>= 1) ss += __shfl_xor(ss, o);
    double inv = 1.0 / fmax(sqrt(ss), 1e-12);
    if (lane == 0) inv64[row] = inv;
    float invf = (float)inv;
    short* ob = AB + (size_t)r * DIM;
    ushort4 o0, o1, o2;
    o0.x = (unsigned short)f2bf(x0.x*invf); o0.y = (unsigned short)f2bf(x0.y*invf);
    o0.z = (unsigned short)f2bf(x0.z*invf); o0.w = (unsigned short)f2bf(x0.w*invf);
    o1.x = (unsigned short)f2bf(x1.x*invf); o1.y = (unsigned short)f2bf(x1.y*invf);
    o1.z = (unsigned short)f2bf(x1.z*invf); o1.w = (unsigned short)f2bf(x1.w*invf);
    o2.x = (unsigned short)f2bf(x2.x*invf); o2.y = (unsigned short)f2bf(x2.y*invf);
    o2.z = (unsigned short)f2bf(x2.z*invf); o2.w = (unsigned short)f2bf(x2.w*invf);
    *(ushort4*)&ob[lane * 4]           = o0;
    *(ushort4*)&ob[(lane + 64) * 4]    = o1;
    *(ushort4*)&ob[(lane + 128) * 4]   = o2;
}

// ---------------------------------------------------------------------------
// prep_maskT: float mask [1024][128000] -> TRANSPOSED bits [4000][1024]
// ---------------------------------------------------------------------------
__global__ __launch_bounds__(256, 4) void prep_maskT_k(
    const float* __restrict__ mask, unsigned* __restrict__ bitsT)
{
    int r = blockIdx.x * 256 + threadIdx.x;
    int w0 = blockIdx.y * 40;
    const float* mr = mask + (size_t)r * NANS;
    for (int w = w0; w < w0 + 40; ++w) {
        const float4* p = (const float4*)(mr + w * 32);
        unsigned b = 0;
        #pragma unroll
        for (int q = 0; q < 8; ++q) {
            float4 v = p[q];
            b |= ((unsigned)(v.x != 0.f)) << (q*4+0);
            b |= ((unsigned)(v.y != 0.f)) << (q*4+1);
            b |= ((unsigned)(v.z != 0.f)) << (q*4+2);
            b |= ((unsigned)(v.w != 0.f)) << (q*4+3);
        }
        bitsT[(size_t)w * BATCH + r] = b;
    }
}

// ---------------------------------------------------------------------------
// gemmA_k: PURE m97-structure MFMA GEMM -> raw scores to global.
// ---------------------------------------------------------------------------
__global__ __launch_bounds__(256, 2) void gemmA_k(
    const short* __restrict__ Pb,       // [1024][768] unit-norm bf16
    const short* __restrict__ AB,       // chunk rows, unit-norm bf16
    float* __restrict__ SC,             // [nt128*128][1024]
    int nt128)
{
    __shared__ __align__(16) char smem[33792];
    short* a_sh = (short*)smem;                 // [128][32] = 8192 B
    short* b_sh = (short*)(smem + 8192);        // [128][32] = 8192 B
    float* scl  = (float*)smem;                 // reuse after loop: [64][132]

    int bid = blockIdx.x;
    int v = (bid & 7) * nt128 + (bid >> 3);
    int at = v >> 3, bt = v & 7;
    int a0l = at * 128, b0 = bt * 128;

    int t = threadIdx.x;
    int lane = t & 63, wid = t >> 6;
    int wm = wid & 1, wn = wid >> 1;            // 2x2 wave grid of 64x64
    int lr = lane & 15, lg = lane >> 4;

    const char* gA0 = (const char*)(AB + (size_t)(a0l + (t >> 2)) * DIM + (t & 3) * 8);
    const char* gA1 = (const char*)(AB + (size_t)(a0l + 64 + (t >> 2)) * DIM + (t & 3) * 8);
    const char* gB0 = (const char*)(Pb + (size_t)(b0 + (t >> 2)) * DIM + (t & 3) * 8);
    const char* gB1 = (const char*)(Pb + (size_t)(b0 + 64 + (t >> 2)) * DIM + (t & 3) * 8);
    char* la0 = (char*)a_sh + t * 16;
    char* la1 = (char*)a_sh + 4096 + t * 16;
    char* lb0 = (char*)b_sh + t * 16;
    char* lb1 = (char*)b_sh + 4096 + t * 16;

    f32x4 acc[4][4];
    #pragma unroll
    for (int i = 0; i < 4; ++i)
        #pragma unroll
        for (int j = 0; j < 4; ++j)
            acc[i][j] = (f32x4){0.f, 0.f, 0.f, 0.f};

    for (int kt = 0; kt < 24; ++kt) {
        gload16(gA0, la0);
        gload16(gA1, la1);
        gload16(gB0, lb0);
        gload16(gB1, lb1);
        gA0 += 64; gA1 += 64; gB0 += 64; gB1 += 64;
        __syncthreads();                        // drain vmcnt + barrier
        bf16x8 af[4], bg[4];
        #pragma unroll
        for (int mt = 0; mt < 4; ++mt)
            af[mt] = *(const bf16x8*)(a_sh + (wm*64 + mt*16 + lr) * 32 + lg*8);
        #pragma unroll
        for (int nt = 0; nt < 4; ++nt)
            bg[nt] = *(const bf16x8*)(b_sh + (wn*64 + nt*16 + lr) * 32 + lg*8);
        #pragma unroll
        for (int mt = 0; mt < 4; ++mt)
            #pragma unroll
            for (int nt = 0; nt < 4; ++nt)
                acc[mt][nt] = __builtin_amdgcn_mfma_f32_16x16x32_bf16(
                    af[mt], bg[nt], acc[mt][nt], 0, 0, 0);
        __syncthreads();                        // reads done before next stage
    }

    // ---- epilogue: dump 64-answer chunks via LDS, coalesced f4 stores ----
    int rloc = t >> 5, c4 = t & 31;
    for (int c = 0; c < 2; ++c) {
        __syncthreads();
        if (wm == c) {
            #pragma unroll
            for (int nt = 0; nt < 4; ++nt) {
                int lcol = wn * 64 + nt * 16 + lr;
                #pragma unroll
                for (int mt = 0; mt < 4; ++mt) {
                    int lrow = mt * 16 + lg * 4;
                    scl[(lrow + 0) * 132 + lcol] = acc[mt][nt][0];
                    scl[(lrow + 1) * 132 + lcol] = acc[mt][nt][1];
                    scl[(lrow + 2) * 132 + lcol] = acc[mt][nt][2];
                    scl[(lrow + 3) * 132 + lcol] = acc[mt][nt][3];
                }
            }
        }
        __syncthreads();
        #pragma unroll
        for (int i = 0; i < 8; ++i) {
            int row = i * 8 + rloc;
            float4 val = *(const float4*)&scl[row * 132 + c4 * 4];
            *(float4*)&SC[(size_t)(a0l + c * 64 + row) * BATCH + b0 + c4 * 4] = val;
        }
    }
}

// ---------------------------------------------------------------------------
// selB_k: stream scores + bitmask -> per-(row, 128-tile) top-10 shortlist.
// Thread = one batch row. Top-10 in NAMED registers (no arrays -> no scratch).
// ---------------------------------------------------------------------------
__global__ __launch_bounds__(256, 4) void selB_k(
    const float* __restrict__ SC,       // [nt128*128][1024] chunk-local
    const unsigned* __restrict__ bitsT, // [4000][1024]
    float* __restrict__ cs2, int* __restrict__ ci2,  // [1000][1024][10]
    int t128_0, int nt128)
{
    int r = blockIdx.x * 256 + threadIdx.x;     // batch row
    for (int s = 0; s < 2; ++s) {
        int tl = blockIdx.y * 2 + s;            // chunk-local tile
        if (tl >= nt128) break;
        int gt = t128_0 + tl;                   // global tile
        Top10 t;
        t10_init(t);
        const float* sc = SC + (size_t)tl * 128 * BATCH + r;
        #pragma unroll
        for (int c = 0; c < 4; ++c) {
            unsigned wv = bitsT[(size_t)(gt * 4 + c) * BATCH + r];
            const float* scc = sc + (size_t)c * 32 * BATCH;
            #pragma unroll
            for (int i = 0; i < 32; ++i) {
                float vsc = scc[(size_t)i * BATCH];
                vsc = ((wv >> i) & 1u) ? vsc : 0.0f;
                t10_ins(t, vsc, gt * 128 + c * 32 + i);
            }
        }
        size_t base = ((size_t)gt * BATCH + r) * 10;
        cs2[base+0]=t.s0; cs2[base+1]=t.s1; cs2[base+2]=t.s2; cs2[base+3]=t.s3;
        cs2[base+4]=t.s4; cs2[base+5]=t.s5; cs2[base+6]=t.s6; cs2[base+7]=t.s7;
        cs2[base+8]=t.s8; cs2[base+9]=t.s9;
        ci2[base+0]=t.i0; ci2[base+1]=t.i1; ci2[base+2]=t.i2; ci2[base+3]=t.i3;
        ci2[base+4]=t.i4; ci2[base+5]=t.i5; ci2[base+6]=t.i6; ci2[base+7]=t.i7;
        ci2[base+8]=t.i8; ci2[base+9]=t.i9;
    }
}

// ---------------------------------------------------------------------------
// merge_rescore2: stream 10000 cands -> per-thread top-16 (NAMED regs) ->
// LDS 4096 -> global top-16 -> fp64 rescore -> final top-10 + gather.
// ---------------------------------------------------------------------------
__global__ __launch_bounds__(256) void merge_rescore2_k(
    const float* __restrict__ cs2, const int* __restrict__ ci2,
    const float* __restrict__ P, const float* __restrict__ ANS,
    const double* __restrict__ invn64, const float* __restrict__ mask,
    float* __restrict__ out)
{
    __shared__ float  ls[4096];
    __shared__ int    li[4096];
    __shared__ float  rrs[4];
    __shared__ int    rri[4], rrp[4];
    __shared__ int    topi_s[16];
    __shared__ double tops_s[16];
    __shared__ int    fin_s[10];
    int row = blockIdx.x, tid = threadIdx.x;

    Top16 t;
    t16_init(t);
    for (int gt = tid; gt < NT128; gt += 256) {
        size_t base = ((size_t)gt * BATCH + row) * 10;
        #pragma unroll
        for (int k = 0; k < 10; ++k)
            t16_ins(t, cs2[base + k], ci2[base + k]);
    }
    {
        int o = tid * 16;
        ls[o+0]=t.s0;  ls[o+1]=t.s1;  ls[o+2]=t.s2;  ls[o+3]=t.s3;
        ls[o+4]=t.s4;  ls[o+5]=t.s5;  ls[o+6]=t.s6;  ls[o+7]=t.s7;
        ls[o+8]=t.s8;  ls[o+9]=t.s9;  ls[o+10]=t.s10; ls[o+11]=t.s11;
        ls[o+12]=t.s12; ls[o+13]=t.s13; ls[o+14]=t.s14; ls[o+15]=t.s15;
        li[o+0]=t.i0;  li[o+1]=t.i1;  li[o+2]=t.i2;  li[o+3]=t.i3;
        li[o+4]=t.i4;  li[o+5]=t.i5;  li[o+6]=t.i6;  li[o+7]=t.i7;
        li[o+8]=t.i8;  li[o+9]=t.i9;  li[o+10]=t.i10; li[o+11]=t.i11;
        li[o+12]=t.i12; li[o+13]=t.i13; li[o+14]=t.i14; li[o+15]=t.i15;
    }
    __syncthreads();

    for (int it = 0; it < 16; ++it) {
        float bsv = -INFINITY; int bi = 0x7fffffff, bp = -1;
        for (int j = tid; j < 4096; j += 256) {
            float s = ls[j];
            if (s > bsv || (s == bsv && li[j] < bi)) { bsv = s; bi = li[j]; bp = j; }
        }
        #pragma unroll
        for (int o = 32; o; o >>= 1) {
            float os = __shfl_down(bsv, o);
            int oi = __shfl_down(bi, o);
            int op = __shfl_down(bp, o);
            if (os > bsv || (os == bsv && oi < bi)) { bsv = os; bi = oi; bp = op; }
        }
        if ((tid & 63) == 0) { int w = tid >> 6; rrs[w] = bsv; rri[w] = bi; rrp[w] = bp; }
        __syncthreads();
        if (tid == 0) {
            for (int w = 1; w < 4; ++w)
                if (rrs[w] > bsv || (rrs[w] == bsv && rri[w] < bi)) {
                    bsv = rrs[w]; bi = rri[w]; bp = rrp[w];
                }
            topi_s[it] = bi;
            ls[bp] = -INFINITY;
        }
        __syncthreads();
    }

    // fp64 rescore: 16 threads per candidate
    int c = tid >> 4, part = tid & 15;
    int aidx = topi_s[c];
    const float4* p4 = (const float4*)(P + (size_t)row * DIM);
    const float4* a4 = (const float4*)(ANS + (size_t)aidx * DIM);
    double sum = 0.0;
    #pragma unroll
    for (int i = 0; i < 12; ++i) {
        float4 pv = p4[part * 12 + i];
        float4 av = a4[part * 12 + i];
        sum += (double)pv.x * av.x + (double)pv.y * av.y
             + (double)pv.z * av.z + (double)pv.w * av.w;
    }
    #pragma unroll
    for (int o = 8; o; o >>= 1) sum += __shfl_down(sum, o, 16);
    if (part == 0) {
        float m = mask[(size_t)row * NANS + aidx];
        tops_s[c] = sum * invn64[aidx] * (double)m;
    }
    __syncthreads();

    if (tid == 0) {
        unsigned used = 0;
        for (int k = 0; k < 10; ++k) {
            int bj = -1;
            for (int j = 0; j < 16; ++j) {
                if (used & (1u << j)) continue;
                if (bj < 0 || tops_s[j] > tops_s[bj] ||
                    (tops_s[j] == tops_s[bj] && topi_s[j] < topi_s[bj])) bj = j;
            }
            used |= 1u << bj;
            out[(size_t)row * 10 + k] = (float)tops_s[bj];
            out[10240 + (size_t)row * 10 + k] = (float)topi_s[bj];
            fin_s[k] = topi_s[bj];
        }
    }
    __syncthreads();

    for (int k = 0; k < 10; ++k) {
        int id = fin_s[k];
        const float* arow = ANS + (size_t)id * DIM;
        float* orow = out + 20480 + ((size_t)(row * 10 + k)) * DIM;
        for (int d = tid; d < DIM; d += 256) orow[d] = arow[d];
    }
}

// ---------------------------------------------------------------------------
extern "C" void kernel_launch(void* const* d_in, const int* in_sizes, int n_in,
                              void* d_out, int out_size, void* d_ws, size_t ws_size,
                              hipStream_t stream)
{
    (void)in_sizes; (void)n_in; (void)out_size;
    const float* visual = (const float*)d_in[0];
    const float* mask   = (const float*)d_in[2];
    const float* ans    = (const float*)d_in[3];
    const float* wv = (const float*)d_in[8];
    const float* bv = (const float*)d_in[9];
    const float* wo = (const float*)d_in[10];
    const float* bo = (const float*)d_in[11];
    const float* fw = (const float*)d_in[12];
    const float* fb = (const float*)d_in[13];
    const float* lg = (const float*)d_in[14];
    const float* lb = (const float*)d_in[15];
    const float* sw = (const float*)d_in[16];
    const float* sb = (const float*)d_in[17];
    float* out = (float*)d_out;

    // ---- workspace: persistent first; transient upstream + AB/SC share tail ----
    char* w = (char*)d_ws;
    float*    P      = (float*)w;    w += (size_t)BATCH * DIM * 4;          // 3.1 MB
    short*    Pb     = (short*)w;    w += (size_t)BATCH * DIM * 2;          // 1.6 MB
    double*   invn64 = (double*)w;   w += (size_t)NANS * 8;                 // 1.0 MB
    float*    cs2    = (float*)w;    w += (size_t)NT128 * BATCH * 10 * 4;   // 41 MB
    int*      ci2    = (int*)w;      w += (size_t)NT128 * BATCH * 10 * 4;   // 41 MB
    unsigned* bitsT  = (unsigned*)w; w += (size_t)NWORDS * BATCH * 4;       // 16.4 MB
    char*     tail   = w;
    float*    fused_in = (float*)tail;
    float*    v        = fused_in + (size_t)BATCH * 1536;
    float*    h        = v + (size_t)BATCH * DIM;

    // per-128-tile chunk bytes: AB (128*768*2) + SC (128*1024*4)
    size_t ab_t = (size_t)128 * DIM * 2;        // 196608
    size_t sc_t = (size_t)128 * BATCH * 4;      // 524288
    size_t used = (size_t)(tail - (char*)d_ws);
    size_t avail = (ws_size > used) ? (ws_size - used) : 2 * (ab_t + sc_t);
    int CT = (int)(avail / (ab_t + sc_t));      // tiles per chunk
    CT &= ~1;                                   // even
    if (CT < 2) CT = 2;
    if (CT > NT128) CT = NT128;
    int nch = (NT128 + CT - 1) / CT;

    copy_visual_k<<<512, 256, 0, stream>>>(visual, fused_in);
    gemm_bias_k<<<dim3(16, 12), 256, 0, stream>>>(visual, DIM, wv, bv, v, DIM, DIM);
    gemm_bias_k<<<dim3(16, 12), 256, 0, stream>>>(v, DIM, wo, bo, fused_in + DIM, 1536, DIM);
    gemm_bias_k<<<dim3(16, 12), 256, 0, stream>>>(fused_in, 1536, fw, fb, h, DIM, 1536);
    ln_gelu_k<<<BATCH, 256, 0, stream>>>(h, lg, lb);
    gemm_bias_k<<<dim3(16, 12), 256, 0, stream>>>(h, DIM, sw, sb, P, DIM, DIM);
    l2norm_bf_k<<<BATCH, 256, 0, stream>>>(P, Pb);
    prep_maskT_k<<<dim3(4, 100), 256, 0, stream>>>(mask, bitsT);
    // ---- upstream transients dead from here; AB/SC reuse the tail ----
    short* AB = (short*)tail;
    float* SC = (float*)(tail + (size_t)CT * ab_t);

    for (int ch = 0; ch < nch; ++ch) {
        int t0 = ch * CT;
        int n = NT128 - t0; if (n > CT) n = CT;
        int nrows = n * 128;
        prep_ans_k<<<(nrows + 3) / 4, 256, 0, stream>>>(ans, t0 * 128, nrows,
                                                        invn64, AB);
        gemmA_k<<<n * 8, 256, 0, stream>>>(Pb, AB, SC, n);
        selB_k<<<dim3(4, (n + 1) / 2), 256, 0, stream>>>(SC, bitsT, cs2, ci2, t0, n);
    }

    merge_rescore2_k<<<BATCH, 256, 0, stream>>>(cs2, ci2, P, ans, invn64, mask, out);
}

// Round 12
// 1492.585 us; speedup vs baseline: 2.9074x; 1.1508x over previous
//
#include <hip/hip_runtime.h>
#include <math.h>

#define DIM    768
#define BATCH  1024
#define NANS   128000
#define NT128  1000             // 128-answer shortlist tiles
#define NWORDS 4000             // mask bit-words per batch row (128000/32)

typedef short  bf16x8 __attribute__((ext_vector_type(8)));
typedef float  f32x4  __attribute__((ext_vector_type(4)));

__device__ __forceinline__ short f2bf(float x)
{
    unsigned u = __builtin_bit_cast(unsigned, x);
    u += 0x7fffu + ((u >> 16) & 1u);          // RNE (no NaN inputs here)
    return (short)(u >> 16);
}

__device__ __forceinline__ void gload16(const void* g, void* l)
{
    __builtin_amdgcn_global_load_lds(
        (const __attribute__((address_space(1))) void*)g,
        (__attribute__((address_space(3))) void*)l, 16, 0, 0);
}

// ---------------------------------------------------------------------------
// Register-resident top-K: NAMED scalar slots (no arrays -> no scratch).
// Tie rule: equal score -> lower index ranks higher (matches np/jax top_k).
// ---------------------------------------------------------------------------
struct Top10 {
    float s0,s1,s2,s3,s4,s5,s6,s7,s8,s9;
    int   i0,i1,i2,i3,i4,i5,i6,i7,i8,i9;
};
__device__ __forceinline__ void t10_init(Top10& t)
{
    t.s0=t.s1=t.s2=t.s3=t.s4=t.s5=t.s6=t.s7=t.s8=t.s9=-INFINITY;
    t.i0=t.i1=t.i2=t.i3=t.i4=t.i5=t.i6=t.i7=t.i8=t.i9=0x7fffffff;
}
__device__ __forceinline__ void t10_ins(Top10& t, float v, int vi)
{
#define T10_STEP(S,I) { bool g=(v>t.S)||(v==t.S&&vi<t.I); \
    float ts_=t.S; int ti_=t.I; \
    t.S=g?v:t.S; t.I=g?vi:t.I; v=g?ts_:v; vi=g?ti_:vi; }
    T10_STEP(s0,i0) T10_STEP(s1,i1) T10_STEP(s2,i2) T10_STEP(s3,i3)
    T10_STEP(s4,i4) T10_STEP(s5,i5) T10_STEP(s6,i6) T10_STEP(s7,i7)
    T10_STEP(s8,i8) T10_STEP(s9,i9)
#undef T10_STEP
}

struct Top16 {
    float s0,s1,s2,s3,s4,s5,s6,s7,s8,s9,s10,s11,s12,s13,s14,s15;
    int   i0,i1,i2,i3,i4,i5,i6,i7,i8,i9,i10,i11,i12,i13,i14,i15;
};
__device__ __forceinline__ void t16_init(Top16& t)
{
    t.s0=t.s1=t.s2=t.s3=t.s4=t.s5=t.s6=t.s7=-INFINITY;
    t.s8=t.s9=t.s10=t.s11=t.s12=t.s13=t.s14=t.s15=-INFINITY;
    t.i0=t.i1=t.i2=t.i3=t.i4=t.i5=t.i6=t.i7=0x7fffffff;
    t.i8=t.i9=t.i10=t.i11=t.i12=t.i13=t.i14=t.i15=0x7fffffff;
}
__device__ __forceinline__ void t16_ins(Top16& t, float v, int vi)
{
#define T16_STEP(S,I) { bool g=(v>t.S)||(v==t.S&&vi<t.I); \
    float ts_=t.S; int ti_=t.I; \
    t.S=g?v:t.S; t.I=g?vi:t.I; v=g?ts_:v; vi=g?ti_:vi; }
    T16_STEP(s0,i0)   T16_STEP(s1,i1)   T16_STEP(s2,i2)   T16_STEP(s3,i3)
    T16_STEP(s4,i4)   T16_STEP(s5,i5)   T16_STEP(s6,i6)   T16_STEP(s7,i7)
    T16_STEP(s8,i8)   T16_STEP(s9,i9)   T16_STEP(s10,i10) T16_STEP(s11,i11)
    T16_STEP(s12,i12) T16_STEP(s13,i13) T16_STEP(s14,i14) T16_STEP(s15,i15)
#undef T16_STEP
}

// ---------------------------------------------------------------------------
// Upstream GEMM: C[M,N] = A[M,K] @ W[N,K]^T + bias   (fp32)
// ---------------------------------------------------------------------------
__global__ __launch_bounds__(256, 2) void gemm_bias_k(
    const float* __restrict__ A, int lda,
    const float* __restrict__ W,
    const float* __restrict__ bias,
    float* __restrict__ C, int ldc, int K)
{
    __shared__ float as[32][68];
    __shared__ float bs[32][68];
    int m0 = blockIdx.x * 64, n0 = blockIdx.y * 64;
    int tid = threadIdx.x;
    int tm = tid & 15, tn = tid >> 4;
    int sr = tid >> 3, skq = tid & 7;
    float acc[4][4] = {};
    for (int k0 = 0; k0 < K; k0 += 32) {
        __syncthreads();
        #pragma unroll
        for (int p = 0; p < 2; ++p) {
            int r = sr + 32 * p;
            float4 av = *(const float4*)&A[(size_t)(m0 + r) * lda + k0 + skq * 4];
            as[skq*4+0][r] = av.x; as[skq*4+1][r] = av.y;
            as[skq*4+2][r] = av.z; as[skq*4+3][r] = av.w;
            float4 wv = *(const float4*)&W[(size_t)(n0 + r) * K + k0 + skq * 4];
            bs[skq*4+0][r] = wv.x; bs[skq*4+1][r] = wv.y;
            bs[skq*4+2][r] = wv.z; bs[skq*4+3][r] = wv.w;
        }
        __syncthreads();
        #pragma unroll 8
        for (int k = 0; k < 32; ++k) {
            float a4[4], b4[4];
            *(float4*)a4 = *(const float4*)&as[k][tm*4];
            *(float4*)b4 = *(const float4*)&bs[k][tn*4];
            #pragma unroll
            for (int i = 0; i < 4; ++i)
                #pragma unroll
                for (int j = 0; j < 4; ++j)
                    acc[i][j] = fmaf(a4[i], b4[j], acc[i][j]);
        }
    }
    float4 bv4 = *(const float4*)&bias[n0 + tn*4];
    #pragma unroll
    for (int i = 0; i < 4; ++i) {
        float4 c4;
        c4.x = acc[i][0] + bv4.x; c4.y = acc[i][1] + bv4.y;
        c4.z = acc[i][2] + bv4.z; c4.w = acc[i][3] + bv4.w;
        *(float4*)&C[(size_t)(m0 + tm*4 + i) * ldc + n0 + tn*4] = c4;
    }
}

// ---------------------------------------------------------------------------
__global__ void copy_visual_k(const float* __restrict__ src, float* __restrict__ dst)
{
    int idx = blockIdx.x * 256 + threadIdx.x;          // float4 index
    const int total = BATCH * (DIM / 4);
    for (; idx < total; idx += 512 * 256) {
        int b = idx / (DIM / 4), c = idx % (DIM / 4);
        ((float4*)dst)[(size_t)b * (1536 / 4) + c] = ((const float4*)src)[idx];
    }
}

// ---------------------------------------------------------------------------
__device__ __forceinline__ float block_sum(float v, float* red)
{
    #pragma unroll
    for (int o = 32; o; o >>= 1) v += __shfl_down(v, o);
    if ((threadIdx.x & 63) == 0) red[threadIdx.x >> 6] = v;
    __syncthreads();
    float r = red[0] + red[1] + red[2] + red[3];
    __syncthreads();
    return r;
}

__global__ __launch_bounds__(256) void ln_gelu_k(float* __restrict__ H,
        const float* __restrict__ g, const float* __restrict__ b)
{
    __shared__ float red[4];
    int row = blockIdx.x, tid = threadIdx.x;
    float* hr = H + (size_t)row * DIM;
    float v0 = hr[tid], v1 = hr[tid + 256], v2 = hr[tid + 512];
    float mu = block_sum(v0 + v1 + v2, red) * (1.0f / 768.0f);
    float d0 = v0 - mu, d1 = v1 - mu, d2 = v2 - mu;
    float var = block_sum(d0*d0 + d1*d1 + d2*d2, red) * (1.0f / 768.0f);
    float rinv = 1.0f / sqrtf(var + 1e-5f);
    #pragma unroll
    for (int q = 0; q < 3; ++q) {
        int d = tid + 256 * q;
        float dd = (q == 0 ? d0 : (q == 1 ? d1 : d2));
        float y = dd * rinv * g[d] + b[d];
        hr[d] = 0.5f * y * (1.0f + erff(y * 0.70710678118654752f));
    }
}

// l2-normalize P in place, also emit bf16 copy
__global__ __launch_bounds__(256) void l2norm_bf_k(float* __restrict__ P,
        short* __restrict__ Pb)
{
    __shared__ float red[4];
    int row = blockIdx.x, tid = threadIdx.x;
    float* pr = P + (size_t)row * DIM;
    short* pb = Pb + (size_t)row * DIM;
    float v0 = pr[tid], v1 = pr[tid + 256], v2 = pr[tid + 512];
    float ss = block_sum(v0*v0 + v1*v1 + v2*v2, red);
    float inv = 1.0f / fmaxf(sqrtf(ss), 1e-12f);
    v0 *= inv; v1 *= inv; v2 *= inv;
    pr[tid] = v0; pr[tid + 256] = v1; pr[tid + 512] = v2;
    pb[tid] = f2bf(v0); pb[tid + 256] = f2bf(v1); pb[tid + 512] = f2bf(v2);
}

// ---------------------------------------------------------------------------
// prep_ans: fp64 row norm -> inv64[row]; unit-normalized bf16 rows into AB.
// ---------------------------------------------------------------------------
__global__ __launch_bounds__(256) void prep_ans_k(
    const float* __restrict__ ANS, int row0, int nrows,
    double* __restrict__ inv64, short* __restrict__ AB)
{
    int r = blockIdx.x * 4 + (threadIdx.x >> 6);
    if (r >= nrows) return;
    int row = row0 + r;
    int lane = threadIdx.x & 63;
    const float4* a4 = (const float4*)(ANS + (size_t)row * DIM);
    float4 x0 = a4[lane], x1 = a4[lane + 64], x2 = a4[lane + 128];
    double ss = (double)x0.x*x0.x + (double)x0.y*x0.y + (double)x0.z*x0.z + (double)x0.w*x0.w
              + (double)x1.x*x1.x + (double)x1.y*x1.y + (double)x1.z*x1.z + (double)x1.w*x1.w
              + (double)x2.x*x2.x + (double)x2.y*x2.y + (double)x2.z*x2.z + (double)x2.w*x2.w;
    #pragma unroll
    for (int o = 32; o; o >>= 1) ss += __shfl_xor(ss, o);
    double inv = 1.0 / fmax(sqrt(ss), 1e-12);
    if (lane == 0) inv64[row] = inv;
    float invf = (float)inv;
    short* ob = AB + (size_t)r * DIM;
    ushort4 o0, o1, o2;
    o0.x = (unsigned short)f2bf(x0.x*invf); o0.y = (unsigned short)f2bf(x0.y*invf);
    o0.z = (unsigned short)f2bf(x0.z*invf); o0.w = (unsigned short)f2bf(x0.w*invf);
    o1.x = (unsigned short)f2bf(x1.x*invf); o1.y = (unsigned short)f2bf(x1.y*invf);
    o1.z = (unsigned short)f2bf(x1.z*invf); o1.w = (unsigned short)f2bf(x1.w*invf);
    o2.x = (unsigned short)f2bf(x2.x*invf); o2.y = (unsigned short)f2bf(x2.y*invf);
    o2.z = (unsigned short)f2bf(x2.z*invf); o2.w = (unsigned short)f2bf(x2.w*invf);
    *(ushort4*)&ob[lane * 4]           = o0;
    *(ushort4*)&ob[(lane + 64) * 4]    = o1;
    *(ushort4*)&ob[(lane + 128) * 4]   = o2;
}

// ---------------------------------------------------------------------------
// prep_maskT: float mask [1024][128000] -> TRANSPOSED bits [4000][1024]
// ---------------------------------------------------------------------------
__global__ __launch_bounds__(256, 4) void prep_maskT_k(
    const float* __restrict__ mask, unsigned* __restrict__ bitsT)
{
    int r = blockIdx.x * 256 + threadIdx.x;
    int w0 = blockIdx.y * 40;
    const float* mr = mask + (size_t)r * NANS;
    for (int w = w0; w < w0 + 40; ++w) {
        const float4* p = (const float4*)(mr + w * 32);
        unsigned b = 0;
        #pragma unroll
        for (int q = 0; q < 8; ++q) {
            float4 v = p[q];
            b |= ((unsigned)(v.x != 0.f)) << (q*4+0);
            b |= ((unsigned)(v.y != 0.f)) << (q*4+1);
            b |= ((unsigned)(v.z != 0.f)) << (q*4+2);
            b |= ((unsigned)(v.w != 0.f)) << (q*4+3);
        }
        bitsT[(size_t)w * BATCH + r] = b;
    }
}

// ---------------------------------------------------------------------------
// gemmsel_k: fused m97-structure MFMA GEMM + mask + per-(row,tile) top-10.
// 256 thr / 4 waves; tile 128 answers x 128 batch; BK=32; 24 K-steps.
// Epilogue: dump acc chunks to LDS, per-column scan with NAMED-reg Top10
// (scratch-free, the R10->R11-proven fix), bitsT lookup (coalesced),
// 2-subtop merge via LDS, shortlist written in [row][tile][10] layout.
// ---------------------------------------------------------------------------
__global__ __launch_bounds__(256, 2) void gemmsel_k(
    const short* __restrict__ Pb,       // [1024][768] unit-norm bf16
    const short* __restrict__ AB,       // chunk rows, unit-norm bf16
    const unsigned* __restrict__ bitsT, // [4000][1024]
    float* __restrict__ csR, int* __restrict__ ciR,  // [1024][1000*10]
    int t128_0, int nt128)
{
    __shared__ __align__(16) char smem[33792];
    short* a_sh = (short*)smem;                 // [128][32] = 8192 B
    short* b_sh = (short*)(smem + 8192);        // [128][32] = 8192 B
    float* scl  = (float*)smem;                 // reuse: [64][132] = 33792 B
    float* ms   = (float*)smem;                 // reuse: [128][20] f32
    int*   mi   = (int*)(smem + 10240);         // reuse: [128][20] i32

    int bid = blockIdx.x;
    int v = (bid & 7) * nt128 + (bid >> 3);
    int at = v >> 3, bt = v & 7;
    int gt = t128_0 + at;                       // global 128-tile id
    int a0l = at * 128, b0 = bt * 128;

    int tid = threadIdx.x;
    int lane = tid & 63, wid = tid >> 6;
    int wm = wid & 1, wn = wid >> 1;            // 2x2 wave grid of 64x64
    int lr = lane & 15, lg = lane >> 4;

    const char* gA0 = (const char*)(AB + (size_t)(a0l + (tid >> 2)) * DIM + (tid & 3) * 8);
    const char* gA1 = (const char*)(AB + (size_t)(a0l + 64 + (tid >> 2)) * DIM + (tid & 3) * 8);
    const char* gB0 = (const char*)(Pb + (size_t)(b0 + (tid >> 2)) * DIM + (tid & 3) * 8);
    const char* gB1 = (const char*)(Pb + (size_t)(b0 + 64 + (tid >> 2)) * DIM + (tid & 3) * 8);
    char* la0 = (char*)a_sh + tid * 16;
    char* la1 = (char*)a_sh + 4096 + tid * 16;
    char* lb0 = (char*)b_sh + tid * 16;
    char* lb1 = (char*)b_sh + 4096 + tid * 16;

    f32x4 acc[4][4];
    #pragma unroll
    for (int i = 0; i < 4; ++i)
        #pragma unroll
        for (int j = 0; j < 4; ++j)
            acc[i][j] = (f32x4){0.f, 0.f, 0.f, 0.f};

    for (int kt = 0; kt < 24; ++kt) {
        gload16(gA0, la0);
        gload16(gA1, la1);
        gload16(gB0, lb0);
        gload16(gB1, lb1);
        gA0 += 64; gA1 += 64; gB0 += 64; gB1 += 64;
        __syncthreads();                        // drain vmcnt + barrier
        bf16x8 af[4], bg[4];
        #pragma unroll
        for (int mt = 0; mt < 4; ++mt)
            af[mt] = *(const bf16x8*)(a_sh + (wm*64 + mt*16 + lr) * 32 + lg*8);
        #pragma unroll
        for (int nt = 0; nt < 4; ++nt)
            bg[nt] = *(const bf16x8*)(b_sh + (wn*64 + nt*16 + lr) * 32 + lg*8);
        #pragma unroll
        for (int mt = 0; mt < 4; ++mt)
            #pragma unroll
            for (int nt = 0; nt < 4; ++nt)
                acc[mt][nt] = __builtin_amdgcn_mfma_f32_16x16x32_bf16(
                    af[mt], bg[nt], acc[mt][nt], 0, 0, 0);
        __syncthreads();                        // reads done before next stage
    }

    // ---- epilogue: bitmask + per-column top-10 (named regs, no scratch) ----
    Top10 tp;
    t10_init(tp);
    int col = tid & 127, qt = tid >> 7;         // 2 threads per column

    for (int c = 0; c < 2; ++c) {               // 64-answer chunks
        __syncthreads();
        if (wm == c) {                          // 2 waves dump their quadrants
            #pragma unroll
            for (int nt = 0; nt < 4; ++nt) {
                int lcol = wn * 64 + nt * 16 + lr;
                #pragma unroll
                for (int mt = 0; mt < 4; ++mt) {
                    int lrow = mt * 16 + lg * 4;
                    scl[(lrow + 0) * 132 + lcol] = acc[mt][nt][0];
                    scl[(lrow + 1) * 132 + lcol] = acc[mt][nt][1];
                    scl[(lrow + 2) * 132 + lcol] = acc[mt][nt][2];
                    scl[(lrow + 3) * 132 + lcol] = acc[mt][nt][3];
                }
            }
        }
        __syncthreads();
        unsigned wv = bitsT[(size_t)(gt * 4 + c * 2 + qt) * BATCH + b0 + col];
        #pragma unroll
        for (int i = 0; i < 32; ++i) {
            int lrow = qt * 32 + i;
            float sc = scl[lrow * 132 + col];
            sc = ((wv >> i) & 1u) ? sc : 0.0f;
            t10_ins(tp, sc, gt * 128 + c * 64 + lrow);
        }
    }

    __syncthreads();                            // scl dead; reuse for merge
    {
        int o = col * 20 + qt * 10;
        ms[o+0]=tp.s0; ms[o+1]=tp.s1; ms[o+2]=tp.s2; ms[o+3]=tp.s3; ms[o+4]=tp.s4;
        ms[o+5]=tp.s5; ms[o+6]=tp.s6; ms[o+7]=tp.s7; ms[o+8]=tp.s8; ms[o+9]=tp.s9;
        mi[o+0]=tp.i0; mi[o+1]=tp.i1; mi[o+2]=tp.i2; mi[o+3]=tp.i3; mi[o+4]=tp.i4;
        mi[o+5]=tp.i5; mi[o+6]=tp.i6; mi[o+7]=tp.i7; mi[o+8]=tp.i8; mi[o+9]=tp.i9;
    }
    __syncthreads();
    if (tid < 128) {
        Top10 f;
        t10_init(f);
        for (int j = 0; j < 20; ++j)
            t10_ins(f, ms[tid * 20 + j], mi[tid * 20 + j]);
        size_t base = (size_t)(b0 + tid) * (NT128 * 10) + gt * 10;
        csR[base+0]=f.s0; csR[base+1]=f.s1; csR[base+2]=f.s2; csR[base+3]=f.s3;
        csR[base+4]=f.s4; csR[base+5]=f.s5; csR[base+6]=f.s6; csR[base+7]=f.s7;
        csR[base+8]=f.s8; csR[base+9]=f.s9;
        ciR[base+0]=f.i0; ciR[base+1]=f.i1; ciR[base+2]=f.i2; ciR[base+3]=f.i3;
        ciR[base+4]=f.i4; ciR[base+5]=f.i5; ciR[base+6]=f.i6; ciR[base+7]=f.i7;
        ciR[base+8]=f.i8; ciR[base+9]=f.i9;
    }
}

// ---------------------------------------------------------------------------
// merge_rescore3: flat-coalesced stream of this row's 10000 candidates ->
// per-thread top-16 (named regs) -> LDS 4096 -> global top-16 -> fp64 rescore
// -> final top-10 + gather.
// ---------------------------------------------------------------------------
__global__ __launch_bounds__(256) void merge_rescore3_k(
    const float* __restrict__ csR, const int* __restrict__ ciR,
    const float* __restrict__ P, const float* __restrict__ ANS,
    const double* __restrict__ invn64, const float* __restrict__ mask,
    float* __restrict__ out)
{
    __shared__ float  ls[4096];
    __shared__ int    li[4096];
    __shared__ float  rrs[4];
    __shared__ int    rri[4], rrp[4];
    __shared__ int    topi_s[16];
    __shared__ double tops_s[16];
    __shared__ int    fin_s[10];
    int row = blockIdx.x, tid = threadIdx.x;

    Top16 t;
    t16_init(t);
    const float* csr = csR + (size_t)row * (NT128 * 10);
    const int*   cir = ciR + (size_t)row * (NT128 * 10);
    for (int j = tid; j < NT128 * 10; j += 256)
        t16_ins(t, csr[j], cir[j]);
    {
        int o = tid * 16;
        ls[o+0]=t.s0;  ls[o+1]=t.s1;  ls[o+2]=t.s2;  ls[o+3]=t.s3;
        ls[o+4]=t.s4;  ls[o+5]=t.s5;  ls[o+6]=t.s6;  ls[o+7]=t.s7;
        ls[o+8]=t.s8;  ls[o+9]=t.s9;  ls[o+10]=t.s10; ls[o+11]=t.s11;
        ls[o+12]=t.s12; ls[o+13]=t.s13; ls[o+14]=t.s14; ls[o+15]=t.s15;
        li[o+0]=t.i0;  li[o+1]=t.i1;  li[o+2]=t.i2;  li[o+3]=t.i3;
        li[o+4]=t.i4;  li[o+5]=t.i5;  li[o+6]=t.i6;  li[o+7]=t.i7;
        li[o+8]=t.i8;  li[o+9]=t.i9;  li[o+10]=t.i10; li[o+11]=t.i11;
        li[o+12]=t.i12; li[o+13]=t.i13; li[o+14]=t.i14; li[o+15]=t.i15;
    }
    __syncthreads();

    for (int it = 0; it < 16; ++it) {
        float bsv = -INFINITY; int bi = 0x7fffffff, bp = -1;
        for (int j = tid; j < 4096; j += 256) {
            float s = ls[j];
            if (s > bsv || (s == bsv && li[j] < bi)) { bsv = s; bi = li[j]; bp = j; }
        }
        #pragma unroll
        for (int o = 32; o; o >>= 1) {
            float os = __shfl_down(bsv, o);
            int oi = __shfl_down(bi, o);
            int op = __shfl_down(bp, o);
            if (os > bsv || (os == bsv && oi < bi)) { bsv = os; bi = oi; bp = op; }
        }
        if ((tid & 63) == 0) { int w = tid >> 6; rrs[w] = bsv; rri[w] = bi; rrp[w] = bp; }
        __syncthreads();
        if (tid == 0) {
            for (int w = 1; w < 4; ++w)
                if (rrs[w] > bsv || (rrs[w] == bsv && rri[w] < bi)) {
                    bsv = rrs[w]; bi = rri[w]; bp = rrp[w];
                }
            topi_s[it] = bi;
            ls[bp] = -INFINITY;
        }
        __syncthreads();
    }

    // fp64 rescore: 16 threads per candidate
    int c = tid >> 4, part = tid & 15;
    int aidx = topi_s[c];
    const float4* p4 = (const float4*)(P + (size_t)row * DIM);
    const float4* a4 = (const float4*)(ANS + (size_t)aidx * DIM);
    double sum = 0.0;
    #pragma unroll
    for (int i = 0; i < 12; ++i) {
        float4 pv = p4[part * 12 + i];
        float4 av = a4[part * 12 + i];
        sum += (double)pv.x * av.x + (double)pv.y * av.y
             + (double)pv.z * av.z + (double)pv.w * av.w;
    }
    #pragma unroll
    for (int o = 8; o; o >>= 1) sum += __shfl_down(sum, o, 16);
    if (part == 0) {
        float m = mask[(size_t)row * NANS + aidx];
        tops_s[c] = sum * invn64[aidx] * (double)m;
    }
    __syncthreads();

    if (tid == 0) {
        unsigned used = 0;
        for (int k = 0; k < 10; ++k) {
            int bj = -1;
            for (int j = 0; j < 16; ++j) {
                if (used & (1u << j)) continue;
                if (bj < 0 || tops_s[j] > tops_s[bj] ||
                    (tops_s[j] == tops_s[bj] && topi_s[j] < topi_s[bj])) bj = j;
            }
            used |= 1u << bj;
            out[(size_t)row * 10 + k] = (float)tops_s[bj];
            out[10240 + (size_t)row * 10 + k] = (float)topi_s[bj];
            fin_s[k] = topi_s[bj];
        }
    }
    __syncthreads();

    for (int k = 0; k < 10; ++k) {
        int id = fin_s[k];
        const float* arow = ANS + (size_t)id * DIM;
        float* orow = out + 20480 + ((size_t)(row * 10 + k)) * DIM;
        for (int d = tid; d < DIM; d += 256) orow[d] = arow[d];
    }
}

// ---------------------------------------------------------------------------
extern "C" void kernel_launch(void* const* d_in, const int* in_sizes, int n_in,
                              void* d_out, int out_size, void* d_ws, size_t ws_size,
                              hipStream_t stream)
{
    (void)in_sizes; (void)n_in; (void)out_size;
    const float* visual = (const float*)d_in[0];
    const float* mask   = (const float*)d_in[2];
    const float* ans    = (const float*)d_in[3];
    const float* wv = (const float*)d_in[8];
    const float* bv = (const float*)d_in[9];
    const float* wo = (const float*)d_in[10];
    const float* bo = (const float*)d_in[11];
    const float* fw = (const float*)d_in[12];
    const float* fb = (const float*)d_in[13];
    const float* lg = (const float*)d_in[14];
    const float* lb = (const float*)d_in[15];
    const float* sw = (const float*)d_in[16];
    const float* sb = (const float*)d_in[17];
    float* out = (float*)d_out;

    // ---- workspace: persistent first; transient upstream + AB share tail ----
    char* w = (char*)d_ws;
    float*    P      = (float*)w;    w += (size_t)BATCH * DIM * 4;          // 3.1 MB
    short*    Pb     = (short*)w;    w += (size_t)BATCH * DIM * 2;          // 1.6 MB
    double*   invn64 = (double*)w;   w += (size_t)NANS * 8;                 // 1.0 MB
    float*    csR    = (float*)w;    w += (size_t)BATCH * NT128 * 10 * 4;   // 41 MB
    int*      ciR    = (int*)w;      w += (size_t)BATCH * NT128 * 10 * 4;   // 41 MB
    unsigned* bitsT  = (unsigned*)w; w += (size_t)NWORDS * BATCH * 4;       // 16.4 MB
    char*     tail   = w;
    float*    fused_in = (float*)tail;
    float*    v        = fused_in + (size_t)BATCH * 1536;
    float*    h        = v + (size_t)BATCH * DIM;
    short*    AB       = (short*)tail;  // reuses upstream transients after death

    size_t ab_t = (size_t)128 * DIM * 2;        // 196608 B per 128-tile
    size_t used = (size_t)(tail - (char*)d_ws);
    size_t avail = (ws_size > used) ? (ws_size - used) : ab_t;
    int CT = (int)(avail / ab_t);               // tiles per chunk
    if (CT < 1) CT = 1;
    if (CT > NT128) CT = NT128;
    int nch = (NT128 + CT - 1) / CT;

    copy_visual_k<<<512, 256, 0, stream>>>(visual, fused_in);
    gemm_bias_k<<<dim3(16, 12), 256, 0, stream>>>(visual, DIM, wv, bv, v, DIM, DIM);
    gemm_bias_k<<<dim3(16, 12), 256, 0, stream>>>(v, DIM, wo, bo, fused_in + DIM, 1536, DIM);
    gemm_bias_k<<<dim3(16, 12), 256, 0, stream>>>(fused_in, 1536, fw, fb, h, DIM, 1536);
    ln_gelu_k<<<BATCH, 256, 0, stream>>>(h, lg, lb);
    gemm_bias_k<<<dim3(16, 12), 256, 0, stream>>>(h, DIM, sw, sb, P, DIM, DIM);
    l2norm_bf_k<<<BATCH, 256, 0, stream>>>(P, Pb);
    prep_maskT_k<<<dim3(4, 100), 256, 0, stream>>>(mask, bitsT);
    // ---- upstream transients dead from here; AB reuses the tail ----

    for (int ch = 0; ch < nch; ++ch) {
        int t0 = ch * CT;
        int n = NT128 - t0; if (n > CT) n = CT;
        int nrows = n * 128;
        prep_ans_k<<<(nrows + 3) / 4, 256, 0, stream>>>(ans, t0 * 128, nrows,
                                                        invn64, AB);
        gemmsel_k<<<n * 8, 256, 0, stream>>>(Pb, AB, bitsT, csR, ciR, t0, n);
    }

    merge_rescore3_k<<<BATCH, 256, 0, stream>>>(csR, ciR, P, ans, invn64, mask, out);
}

// Round 13
// 1062.459 us; speedup vs baseline: 4.0844x; 1.4048x over previous
//
#include <hip/hip_runtime.h>
#include <math.h>

#define DIM    768
#define BATCH  1024
#define NANS   128000
#define NT128  1000             // 128-answer shortlist tiles
#define NWORDS 4000             // mask bit-words per batch row (128000/32)

typedef short  bf16x8 __attribute__((ext_vector_type(8)));
typedef float  f32x4  __attribute__((ext_vector_type(4)));
typedef unsigned long long u64;

__device__ __forceinline__ short f2bf(float x)
{
    unsigned u = __builtin_bit_cast(unsigned, x);
    u += 0x7fffu + ((u >> 16) & 1u);          // RNE (no NaN inputs here)
    return (short)(u >> 16);
}

__device__ __forceinline__ void gload16(const void* g, void* l)
{
    __builtin_amdgcn_global_load_lds(
        (const __attribute__((address_space(1))) void*)g,
        (__attribute__((address_space(3))) void*)l, 16, 0, 0);
}

// sortable-u32 transform: monotone f32 -> u32 (neg -> ~u, pos -> u|0x80000000)
__device__ __forceinline__ unsigned f2sort(float s)
{
    unsigned u = __builtin_bit_cast(unsigned, s);
    return u ^ ((unsigned)((int)u >> 31) | 0x80000000u);
}

// key = sortable(score)<<32 | (0x7fffffff - idx): u64 compare == (score desc,
// then idx asc) — exactly np/jax top_k tie order. All keys distinct.
struct Top10u { u64 k0,k1,k2,k3,k4,k5,k6,k7,k8,k9; };
__device__ __forceinline__ void t10u_init(Top10u& t)
{ t.k0=t.k1=t.k2=t.k3=t.k4=t.k5=t.k6=t.k7=t.k8=t.k9=0ull; }
__device__ __forceinline__ void t10u_ins(Top10u& t, u64 v)
{
#define TS(K) { bool g = v > t.K; u64 mx = g ? v : t.K; v = g ? t.K : v; t.K = mx; }
    TS(k0) TS(k1) TS(k2) TS(k3) TS(k4) TS(k5) TS(k6) TS(k7) TS(k8) TS(k9)
#undef TS
}

struct Top16u { u64 k0,k1,k2,k3,k4,k5,k6,k7,k8,k9,k10,k11,k12,k13,k14,k15; };
__device__ __forceinline__ void t16u_init(Top16u& t)
{
    t.k0=t.k1=t.k2=t.k3=t.k4=t.k5=t.k6=t.k7=0ull;
    t.k8=t.k9=t.k10=t.k11=t.k12=t.k13=t.k14=t.k15=0ull;
}
__device__ __forceinline__ void t16u_ins(Top16u& t, u64 v)
{
#define TS(K) { bool g = v > t.K; u64 mx = g ? v : t.K; v = g ? t.K : v; t.K = mx; }
    TS(k0)  TS(k1)  TS(k2)  TS(k3)  TS(k4)  TS(k5)  TS(k6)  TS(k7)
    TS(k8)  TS(k9)  TS(k10) TS(k11) TS(k12) TS(k13) TS(k14) TS(k15)
#undef TS
}

// ---------------------------------------------------------------------------
// Upstream GEMM: C[M,N] = A[M,K] @ W[N,K]^T + bias   (fp32)
// ---------------------------------------------------------------------------
__global__ __launch_bounds__(256, 2) void gemm_bias_k(
    const float* __restrict__ A, int lda,
    const float* __restrict__ W,
    const float* __restrict__ bias,
    float* __restrict__ C, int ldc, int K)
{
    __shared__ float as[32][68];
    __shared__ float bs[32][68];
    int m0 = blockIdx.x * 64, n0 = blockIdx.y * 64;
    int tid = threadIdx.x;
    int tm = tid & 15, tn = tid >> 4;
    int sr = tid >> 3, skq = tid & 7;
    float acc[4][4] = {};
    for (int k0 = 0; k0 < K; k0 += 32) {
        __syncthreads();
        #pragma unroll
        for (int p = 0; p < 2; ++p) {
            int r = sr + 32 * p;
            float4 av = *(const float4*)&A[(size_t)(m0 + r) * lda + k0 + skq * 4];
            as[skq*4+0][r] = av.x; as[skq*4+1][r] = av.y;
            as[skq*4+2][r] = av.z; as[skq*4+3][r] = av.w;
            float4 wv = *(const float4*)&W[(size_t)(n0 + r) * K + k0 + skq * 4];
            bs[skq*4+0][r] = wv.x; bs[skq*4+1][r] = wv.y;
            bs[skq*4+2][r] = wv.z; bs[skq*4+3][r] = wv.w;
        }
        __syncthreads();
        #pragma unroll 8
        for (int k = 0; k < 32; ++k) {
            float a4[4], b4[4];
            *(float4*)a4 = *(const float4*)&as[k][tm*4];
            *(float4*)b4 = *(const float4*)&bs[k][tn*4];
            #pragma unroll
            for (int i = 0; i < 4; ++i)
                #pragma unroll
                for (int j = 0; j < 4; ++j)
                    acc[i][j] = fmaf(a4[i], b4[j], acc[i][j]);
        }
    }
    float4 bv4 = *(const float4*)&bias[n0 + tn*4];
    #pragma unroll
    for (int i = 0; i < 4; ++i) {
        float4 c4;
        c4.x = acc[i][0] + bv4.x; c4.y = acc[i][1] + bv4.y;
        c4.z = acc[i][2] + bv4.z; c4.w = acc[i][3] + bv4.w;
        *(float4*)&C[(size_t)(m0 + tm*4 + i) * ldc + n0 + tn*4] = c4;
    }
}

// ---------------------------------------------------------------------------
__global__ void copy_visual_k(const float* __restrict__ src, float* __restrict__ dst)
{
    int idx = blockIdx.x * 256 + threadIdx.x;          // float4 index
    const int total = BATCH * (DIM / 4);
    for (; idx < total; idx += 512 * 256) {
        int b = idx / (DIM / 4), c = idx % (DIM / 4);
        ((float4*)dst)[(size_t)b * (1536 / 4) + c] = ((const float4*)src)[idx];
    }
}

// ---------------------------------------------------------------------------
__device__ __forceinline__ float block_sum(float v, float* red)
{
    #pragma unroll
    for (int o = 32; o; o >>= 1) v += __shfl_down(v, o);
    if ((threadIdx.x & 63) == 0) red[threadIdx.x >> 6] = v;
    __syncthreads();
    float r = red[0] + red[1] + red[2] + red[3];
    __syncthreads();
    return r;
}

__global__ __launch_bounds__(256) void ln_gelu_k(float* __restrict__ H,
        const float* __restrict__ g, const float* __restrict__ b)
{
    __shared__ float red[4];
    int row = blockIdx.x, tid = threadIdx.x;
    float* hr = H + (size_t)row * DIM;
    float v0 = hr[tid], v1 = hr[tid + 256], v2 = hr[tid + 512];
    float mu = block_sum(v0 + v1 + v2, red) * (1.0f / 768.0f);
    float d0 = v0 - mu, d1 = v1 - mu, d2 = v2 - mu;
    float var = block_sum(d0*d0 + d1*d1 + d2*d2, red) * (1.0f / 768.0f);
    float rinv = 1.0f / sqrtf(var + 1e-5f);
    #pragma unroll
    for (int q = 0; q < 3; ++q) {
        int d = tid + 256 * q;
        float dd = (q == 0 ? d0 : (q == 1 ? d1 : d2));
        float y = dd * rinv * g[d] + b[d];
        hr[d] = 0.5f * y * (1.0f + erff(y * 0.70710678118654752f));
    }
}

__global__ __launch_bounds__(256) void l2norm_bf_k(float* __restrict__ P,
        short* __restrict__ Pb)
{
    __shared__ float red[4];
    int row = blockIdx.x, tid = threadIdx.x;
    float* pr = P + (size_t)row * DIM;
    short* pb = Pb + (size_t)row * DIM;
    float v0 = pr[tid], v1 = pr[tid + 256], v2 = pr[tid + 512];
    float ss = block_sum(v0*v0 + v1*v1 + v2*v2, red);
    float inv = 1.0f / fmaxf(sqrtf(ss), 1e-12f);
    v0 *= inv; v1 *= inv; v2 *= inv;
    pr[tid] = v0; pr[tid + 256] = v1; pr[tid + 512] = v2;
    pb[tid] = f2bf(v0); pb[tid + 256] = f2bf(v1); pb[tid + 512] = f2bf(v2);
}

// ---------------------------------------------------------------------------
// prep_ans: fp64 row norm -> inv64[row]; unit-normalized bf16 rows into AB.
// ---------------------------------------------------------------------------
__global__ __launch_bounds__(256) void prep_ans_k(
    const float* __restrict__ ANS, int row0, int nrows,
    double* __restrict__ inv64, short* __restrict__ AB)
{
    int r = blockIdx.x * 4 + (threadIdx.x >> 6);
    if (r >= nrows) return;
    int row = row0 + r;
    int lane = threadIdx.x & 63;
    const float4* a4 = (const float4*)(ANS + (size_t)row * DIM);
    float4 x0 = a4[lane], x1 = a4[lane + 64], x2 = a4[lane + 128];
    double ss = (double)x0.x*x0.x + (double)x0.y*x0.y + (double)x0.z*x0.z + (double)x0.w*x0.w
              + (double)x1.x*x1.x + (double)x1.y*x1.y + (double)x1.z*x1.z + (double)x1.w*x1.w
              + (double)x2.x*x2.x + (double)x2.y*x2.y + (double)x2.z*x2.z + (double)x2.w*x2.w;
    #pragma unroll
    for (int o = 32; o; o >>= 1) ss += __shfl_xor(ss, o);
    double inv = 1.0 / fmax(sqrt(ss), 1e-12);
    if (lane == 0) inv64[row] = inv;
    float invf = (float)inv;
    short* ob = AB + (size_t)r * DIM;
    ushort4 o0, o1, o2;
    o0.x = (unsigned short)f2bf(x0.x*invf); o0.y = (unsigned short)f2bf(x0.y*invf);
    o0.z = (unsigned short)f2bf(x0.z*invf); o0.w = (unsigned short)f2bf(x0.w*invf);
    o1.x = (unsigned short)f2bf(x1.x*invf); o1.y = (unsigned short)f2bf(x1.y*invf);
    o1.z = (unsigned short)f2bf(x1.z*invf); o1.w = (unsigned short)f2bf(x1.w*invf);
    o2.x = (unsigned short)f2bf(x2.x*invf); o2.y = (unsigned short)f2bf(x2.y*invf);
    o2.z = (unsigned short)f2bf(x2.z*invf); o2.w = (unsigned short)f2bf(x2.w*invf);
    *(ushort4*)&ob[lane * 4]           = o0;
    *(ushort4*)&ob[(lane + 64) * 4]    = o1;
    *(ushort4*)&ob[(lane + 128) * 4]   = o2;
}

// ---------------------------------------------------------------------------
// prep_maskT: float mask [1024][128000] -> TRANSPOSED bits [4000][1024]
// ---------------------------------------------------------------------------
__global__ __launch_bounds__(256, 4) void prep_maskT_k(
    const float* __restrict__ mask, unsigned* __restrict__ bitsT)
{
    int r = blockIdx.x * 256 + threadIdx.x;
    int w0 = blockIdx.y * 40;
    const float* mr = mask + (size_t)r * NANS;
    for (int w = w0; w < w0 + 40; ++w) {
        const float4* p = (const float4*)(mr + w * 32);
        unsigned b = 0;
        #pragma unroll
        for (int q = 0; q < 8; ++q) {
            float4 v = p[q];
            b |= ((unsigned)(v.x != 0.f)) << (q*4+0);
            b |= ((unsigned)(v.y != 0.f)) << (q*4+1);
            b |= ((unsigned)(v.z != 0.f)) << (q*4+2);
            b |= ((unsigned)(v.w != 0.f)) << (q*4+3);
        }
        bitsT[(size_t)w * BATCH + r] = b;
    }
}

// ---------------------------------------------------------------------------
// gemmsel_k: fused MFMA GEMM (2-phase dbuf staging) + mask + per-(row,tile)
// top-10 via u64-packed named-reg chains + shfl-pair bitonic merge.
// 256 thr / 4 waves; tile 128 answers x 128 batch; BK=32; 24 K-steps.
// ---------------------------------------------------------------------------
__global__ __launch_bounds__(256, 2) void gemmsel_k(
    const short* __restrict__ Pb,       // [1024][768] unit-norm bf16
    const short* __restrict__ AB,       // chunk rows, unit-norm bf16
    const unsigned* __restrict__ bitsT, // [4000][1024]
    u64* __restrict__ ck,               // [1024][1000*10] packed keys
    int t128_0, int nt128)
{
    __shared__ __align__(16) char smem[33792];
    // staging: 2 bufs x (A [128][32] + B [128][32]) shorts
    //   A buf b at smem + b*8192;  B buf b at smem + 16384 + b*8192
    float* scl = (float*)smem;                  // epilogue reuse: [64][132]

    int bid = blockIdx.x;
    int v = (bid & 7) * nt128 + (bid >> 3);
    int at = v >> 3, bt = v & 7;
    int gt = t128_0 + at;                       // global 128-tile id
    int a0l = at * 128, b0 = bt * 128;

    int tid = threadIdx.x;
    int lane = tid & 63, wid = tid >> 6;
    int wm = wid & 1, wn = wid >> 1;            // 2x2 wave grid of 64x64
    int lr = lane & 15, lg = lane >> 4;

    const char* gA0 = (const char*)(AB + (size_t)(a0l + (tid >> 2)) * DIM + (tid & 3) * 8);
    const char* gA1 = (const char*)(AB + (size_t)(a0l + 64 + (tid >> 2)) * DIM + (tid & 3) * 8);
    const char* gB0 = (const char*)(Pb + (size_t)(b0 + (tid >> 2)) * DIM + (tid & 3) * 8);
    const char* gB1 = (const char*)(Pb + (size_t)(b0 + 64 + (tid >> 2)) * DIM + (tid & 3) * 8);

    f32x4 acc[4][4];
    #pragma unroll
    for (int i = 0; i < 4; ++i)
        #pragma unroll
        for (int j = 0; j < 4; ++j)
            acc[i][j] = (f32x4){0.f, 0.f, 0.f, 0.f};

    // prologue: stage kt=0 into buf 0
    {
        char* la = smem + tid * 16;
        gload16(gA0, la);
        gload16(gA1, la + 4096);
        gload16(gB0, la + 16384);
        gload16(gB1, la + 20480);
    }
    __syncthreads();

    int buf = 0;
    for (int kt = 0; kt < 24; ++kt) {
        if (kt < 23) {                          // stage next tile into buf^1
            int kb = (kt + 1) * 64;
            char* la = smem + (buf ^ 1) * 8192 + tid * 16;
            gload16(gA0 + kb, la);
            gload16(gA1 + kb, la + 4096);
            gload16(gB0 + kb, la + 16384);
            gload16(gB1 + kb, la + 20480);
        }
        const short* a_sh = (const short*)(smem + buf * 8192);
        const short* b_sh = (const short*)(smem + 16384 + buf * 8192);
        bf16x8 af[4], bg[4];
        #pragma unroll
        for (int mt = 0; mt < 4; ++mt)
            af[mt] = *(const bf16x8*)(a_sh + (wm*64 + mt*16 + lr) * 32 + lg*8);
        #pragma unroll
        for (int nt = 0; nt < 4; ++nt)
            bg[nt] = *(const bf16x8*)(b_sh + (wn*64 + nt*16 + lr) * 32 + lg*8);
        #pragma unroll
        for (int mt = 0; mt < 4; ++mt)
            #pragma unroll
            for (int nt = 0; nt < 4; ++nt)
                acc[mt][nt] = __builtin_amdgcn_mfma_f32_16x16x32_bf16(
                    af[mt], bg[nt], acc[mt][nt], 0, 0, 0);
        __syncthreads();                        // drains next-tile loads too
        buf ^= 1;
    }

    // ---- epilogue: bitmask + per-column top-10, u64 keys in named regs ----
    Top10u tp;
    t10u_init(tp);
    int col = tid >> 1, qt = tid & 1;           // pair lanes share a column
    unsigned lob = 0x7fffffffu - (unsigned)(gt * 128) - (unsigned)(qt * 32);
    int qoff = qt * 32;

    for (int c = 0; c < 2; ++c) {               // 64-answer chunks
        __syncthreads();
        if (wm == c) {                          // 2 waves dump their quadrants
            #pragma unroll
            for (int nt = 0; nt < 4; ++nt) {
                int lcol = wn * 64 + nt * 16 + lr;
                #pragma unroll
                for (int mt = 0; mt < 4; ++mt) {
                    int lrow = mt * 16 + lg * 4;
                    scl[(lrow + 0) * 132 + lcol] = acc[mt][nt][0];
                    scl[(lrow + 1) * 132 + lcol] = acc[mt][nt][1];
                    scl[(lrow + 2) * 132 + lcol] = acc[mt][nt][2];
                    scl[(lrow + 3) * 132 + lcol] = acc[mt][nt][3];
                }
            }
        }
        __syncthreads();
        unsigned wv = bitsT[(size_t)(gt * 4 + c * 2 + qt) * BATCH + b0 + col];
        #pragma unroll
        for (int i = 0; i < 32; ++i) {
            float sc = scl[(qoff + i) * 132 + col];
            sc = ((wv >> i) & 1u) ? sc : 0.0f;
            u64 key = ((u64)f2sort(sc) << 32) | (unsigned)(lob - (c * 64 + i));
            t10u_ins(tp, key);
        }
    }

    // pair merge: top-10 of two sorted-desc 10-lists = {max(A[i], B[9-i])}
    u64 q0 = __shfl_xor(tp.k0, 1), q1 = __shfl_xor(tp.k1, 1);
    u64 q2 = __shfl_xor(tp.k2, 1), q3 = __shfl_xor(tp.k3, 1);
    u64 q4 = __shfl_xor(tp.k4, 1), q5 = __shfl_xor(tp.k5, 1);
    u64 q6 = __shfl_xor(tp.k6, 1), q7 = __shfl_xor(tp.k7, 1);
    u64 q8 = __shfl_xor(tp.k8, 1), q9 = __shfl_xor(tp.k9, 1);
    u64 m0 = tp.k0 > q9 ? tp.k0 : q9;
    u64 m1 = tp.k1 > q8 ? tp.k1 : q8;
    u64 m2 = tp.k2 > q7 ? tp.k2 : q7;
    u64 m3 = tp.k3 > q6 ? tp.k3 : q6;
    u64 m4 = tp.k4 > q5 ? tp.k4 : q5;
    u64 m5 = tp.k5 > q4 ? tp.k5 : q4;
    u64 m6 = tp.k6 > q3 ? tp.k6 : q3;
    u64 m7 = tp.k7 > q2 ? tp.k7 : q2;
    u64 m8 = tp.k8 > q1 ? tp.k8 : q1;
    u64 m9 = tp.k9 > q0 ? tp.k9 : q0;
    if (qt == 0) {
        u64* dst = ck + (size_t)(b0 + col) * (NT128 * 10) + (size_t)gt * 10;
        dst[0]=m0; dst[1]=m1; dst[2]=m2; dst[3]=m3; dst[4]=m4;
        dst[5]=m5; dst[6]=m6; dst[7]=m7; dst[8]=m8; dst[9]=m9;
    }
}

// ---------------------------------------------------------------------------
// merge_rescore4: stream row's 10000 packed keys -> per-thread top-16 ->
// LDS 4096 -> global top-16 -> fp64 rescore -> final top-10 + gather.
// ---------------------------------------------------------------------------
__global__ __launch_bounds__(256) void merge_rescore4_k(
    const u64* __restrict__ ck,
    const float* __restrict__ P, const float* __restrict__ ANS,
    const double* __restrict__ invn64, const float* __restrict__ mask,
    float* __restrict__ out)
{
    __shared__ u64    lk[4096];
    __shared__ u64    rrk[4];
    __shared__ int    rrp[4];
    __shared__ int    topi_s[16];
    __shared__ double tops_s[16];
    __shared__ int    fin_s[10];
    int row = blockIdx.x, tid = threadIdx.x;

    Top16u t;
    t16u_init(t);
    const u64* ckr = ck + (size_t)row * (NT128 * 10);
    for (int j = tid; j < NT128 * 10; j += 256)
        t16u_ins(t, ckr[j]);
    {
        int o = tid * 16;
        lk[o+0]=t.k0;  lk[o+1]=t.k1;  lk[o+2]=t.k2;  lk[o+3]=t.k3;
        lk[o+4]=t.k4;  lk[o+5]=t.k5;  lk[o+6]=t.k6;  lk[o+7]=t.k7;
        lk[o+8]=t.k8;  lk[o+9]=t.k9;  lk[o+10]=t.k10; lk[o+11]=t.k11;
        lk[o+12]=t.k12; lk[o+13]=t.k13; lk[o+14]=t.k14; lk[o+15]=t.k15;
    }
    __syncthreads();

    for (int it = 0; it < 16; ++it) {
        u64 bk = 0; int bp = -1;
        for (int j = tid; j < 4096; j += 256) {
            u64 k = lk[j];
            if (k > bk) { bk = k; bp = j; }
        }
        #pragma unroll
        for (int o = 32; o; o >>= 1) {
            u64 ok = __shfl_down(bk, o);
            int op = __shfl_down(bp, o);
            if (ok > bk) { bk = ok; bp = op; }
        }
        if ((tid & 63) == 0) { rrk[tid >> 6] = bk; rrp[tid >> 6] = bp; }
        __syncthreads();
        if (tid == 0) {
            for (int w = 1; w < 4; ++w)
                if (rrk[w] > bk) { bk = rrk[w]; bp = rrp[w]; }
            topi_s[it] = (int)(0x7fffffffu - (unsigned)(bk & 0x7fffffffull));
            lk[bp] = 0;
        }
        __syncthreads();
    }

    // fp64 rescore: 16 threads per candidate
    int c = tid >> 4, part = tid & 15;
    int aidx = topi_s[c];
    const float4* p4 = (const float4*)(P + (size_t)row * DIM);
    const float4* a4 = (const float4*)(ANS + (size_t)aidx * DIM);
    double sum = 0.0;
    #pragma unroll
    for (int i = 0; i < 12; ++i) {
        float4 pv = p4[part * 12 + i];
        float4 av = a4[part * 12 + i];
        sum += (double)pv.x * av.x + (double)pv.y * av.y
             + (double)pv.z * av.z + (double)pv.w * av.w;
    }
    #pragma unroll
    for (int o = 8; o; o >>= 1) sum += __shfl_down(sum, o, 16);
    if (part == 0) {
        float m = mask[(size_t)row * NANS + aidx];
        tops_s[c] = sum * invn64[aidx] * (double)m;
    }
    __syncthreads();

    if (tid == 0) {
        unsigned used = 0;
        for (int k = 0; k < 10; ++k) {
            int bj = -1;
            for (int j = 0; j < 16; ++j) {
                if (used & (1u << j)) continue;
                if (bj < 0 || tops_s[j] > tops_s[bj] ||
                    (tops_s[j] == tops_s[bj] && topi_s[j] < topi_s[bj])) bj = j;
            }
            used |= 1u << bj;
            out[(size_t)row * 10 + k] = (float)tops_s[bj];
            out[10240 + (size_t)row * 10 + k] = (float)topi_s[bj];
            fin_s[k] = topi_s[bj];
        }
    }
    __syncthreads();

    for (int k = 0; k < 10; ++k) {
        int id = fin_s[k];
        const float* arow = ANS + (size_t)id * DIM;
        float* orow = out + 20480 + ((size_t)(row * 10 + k)) * DIM;
        for (int d = tid; d < DIM; d += 256) orow[d] = arow[d];
    }
}

// ---------------------------------------------------------------------------
extern "C" void kernel_launch(void* const* d_in, const int* in_sizes, int n_in,
                              void* d_out, int out_size, void* d_ws, size_t ws_size,
                              hipStream_t stream)
{
    (void)in_sizes; (void)n_in; (void)out_size;
    const float* visual = (const float*)d_in[0];
    const float* mask   = (const float*)d_in[2];
    const float* ans    = (const float*)d_in[3];
    const float* wv = (const float*)d_in[8];
    const float* bv = (const float*)d_in[9];
    const float* wo = (const float*)d_in[10];
    const float* bo = (const float*)d_in[11];
    const float* fw = (const float*)d_in[12];
    const float* fb = (const float*)d_in[13];
    const float* lg = (const float*)d_in[14];
    const float* lb = (const float*)d_in[15];
    const float* sw = (const float*)d_in[16];
    const float* sb = (const float*)d_in[17];
    float* out = (float*)d_out;

    // ---- workspace: persistent first; transient upstream + AB share tail ----
    char* w = (char*)d_ws;
    float*    P      = (float*)w;    w += (size_t)BATCH * DIM * 4;          // 3.1 MB
    short*    Pb     = (short*)w;    w += (size_t)BATCH * DIM * 2;          // 1.6 MB
    double*   invn64 = (double*)w;   w += (size_t)NANS * 8;                 // 1.0 MB
    u64*      ck     = (u64*)w;      w += (size_t)BATCH * NT128 * 10 * 8;   // 82 MB
    unsigned* bitsT  = (unsigned*)w; w += (size_t)NWORDS * BATCH * 4;       // 16.4 MB
    char*     tail   = w;
    float*    fused_in = (float*)tail;
    float*    v        = fused_in + (size_t)BATCH * 1536;
    float*    h        = v + (size_t)BATCH * DIM;
    short*    AB       = (short*)tail;  // reuses upstream transients after death

    size_t ab_t = (size_t)128 * DIM * 2;        // 196608 B per 128-tile
    size_t used = (size_t)(tail - (char*)d_ws);
    size_t avail = (ws_size > used) ? (ws_size - used) : ab_t;
    int CT = (int)(avail / ab_t);               // tiles per chunk
    if (CT < 1) CT = 1;
    if (CT > NT128) CT = NT128;
    int nch = (NT128 + CT - 1) / CT;

    copy_visual_k<<<512, 256, 0, stream>>>(visual, fused_in);
    gemm_bias_k<<<dim3(16, 12), 256, 0, stream>>>(visual, DIM, wv, bv, v, DIM, DIM);
    gemm_bias_k<<<dim3(16, 12), 256, 0, stream>>>(v, DIM, wo, bo, fused_in + DIM, 1536, DIM);
    gemm_bias_k<<<dim3(16, 12), 256, 0, stream>>>(fused_in, 1536, fw, fb, h, DIM, 1536);
    ln_gelu_k<<<BATCH, 256, 0, stream>>>(h, lg, lb);
    gemm_bias_k<<<dim3(16, 12), 256, 0, stream>>>(h, DIM, sw, sb, P, DIM, DIM);
    l2norm_bf_k<<<BATCH, 256, 0, stream>>>(P, Pb);
    prep_maskT_k<<<dim3(4, 100), 256, 0, stream>>>(mask, bitsT);
    // ---- upstream transients dead from here; AB reuses the tail ----

    for (int ch = 0; ch < nch; ++ch) {
        int t0 = ch * CT;
        int n = NT128 - t0; if (n > CT) n = CT;
        int nrows = n * 128;
        prep_ans_k<<<(nrows + 3) / 4, 256, 0, stream>>>(ans, t0 * 128, nrows,
                                                        invn64, AB);
        gemmsel_k<<<n * 8, 256, 0, stream>>>(Pb, AB, bitsT, ck, t0, n);
    }

    merge_rescore4_k<<<BATCH, 256, 0, stream>>>(ck, P, ans, invn64, mask, out);
}

// Round 14
// 965.734 us; speedup vs baseline: 4.4935x; 1.1002x over previous
//
#include <hip/hip_runtime.h>
#include <math.h>

#define DIM    768
#define BATCH  1024
#define NANS   128000
#define NT128  1000             // 128-answer shortlist tiles
#define NWORDS 4000             // mask bit-words per batch row (128000/32)

typedef short  bf16x8 __attribute__((ext_vector_type(8)));
typedef float  f32x4  __attribute__((ext_vector_type(4)));
typedef unsigned long long u64;

__device__ __forceinline__ short f2bf(float x)
{
    unsigned u = __builtin_bit_cast(unsigned, x);
    u += 0x7fffu + ((u >> 16) & 1u);          // RNE (no NaN inputs here)
    return (short)(u >> 16);
}

__device__ __forceinline__ void gload16(const void* g, void* l)
{
    __builtin_amdgcn_global_load_lds(
        (const __attribute__((address_space(1))) void*)g,
        (__attribute__((address_space(3))) void*)l, 16, 0, 0);
}

// sortable-u32 transform: monotone f32 -> u32 (neg -> ~u, pos -> u|0x80000000)
__device__ __forceinline__ unsigned f2sort(float s)
{
    unsigned u = __builtin_bit_cast(unsigned, s);
    return u ^ ((unsigned)((int)u >> 31) | 0x80000000u);
}

__device__ __forceinline__ unsigned umaxu(unsigned a, unsigned b) { return a > b ? a : b; }
__device__ __forceinline__ unsigned uminu(unsigned a, unsigned b) { return a < b ? a : b; }

// u32-packed top-10: key = (sortable(score) & ~0x7F) | (127 - local_idx).
// Insert = v_max_u32 + v_min_u32 per step (2 VALU) — no cndmask, no cmp.
struct Top10k { unsigned k0,k1,k2,k3,k4,k5,k6,k7,k8,k9; };
__device__ __forceinline__ void t10k_init(Top10k& t)
{ t.k0=t.k1=t.k2=t.k3=t.k4=t.k5=t.k6=t.k7=t.k8=t.k9=0u; }
__device__ __forceinline__ void t10k_ins(Top10k& t, unsigned v)
{
#define TS(K) { unsigned mx = umaxu(v, t.K); v = uminu(v, t.K); t.K = mx; }
    TS(k0) TS(k1) TS(k2) TS(k3) TS(k4) TS(k5) TS(k6) TS(k7) TS(k8) TS(k9)
#undef TS
}

// u64 top-16 for the merge phase: v = (key32<<32) | position  (10M inserts)
struct Top16u { u64 k0,k1,k2,k3,k4,k5,k6,k7,k8,k9,k10,k11,k12,k13,k14,k15; };
__device__ __forceinline__ void t16u_init(Top16u& t)
{
    t.k0=t.k1=t.k2=t.k3=t.k4=t.k5=t.k6=t.k7=0ull;
    t.k8=t.k9=t.k10=t.k11=t.k12=t.k13=t.k14=t.k15=0ull;
}
__device__ __forceinline__ void t16u_ins(Top16u& t, u64 v)
{
#define TS(K) { bool g = v > t.K; u64 mx = g ? v : t.K; v = g ? t.K : v; t.K = mx; }
    TS(k0)  TS(k1)  TS(k2)  TS(k3)  TS(k4)  TS(k5)  TS(k6)  TS(k7)
    TS(k8)  TS(k9)  TS(k10) TS(k11) TS(k12) TS(k13) TS(k14) TS(k15)
#undef TS
}

// ---------------------------------------------------------------------------
// Upstream GEMM: C[M,N] = A[M,K] @ W[N,K]^T + bias   (fp32)
// ---------------------------------------------------------------------------
__global__ __launch_bounds__(256, 2) void gemm_bias_k(
    const float* __restrict__ A, int lda,
    const float* __restrict__ W,
    const float* __restrict__ bias,
    float* __restrict__ C, int ldc, int K)
{
    __shared__ float as[32][68];
    __shared__ float bs[32][68];
    int m0 = blockIdx.x * 64, n0 = blockIdx.y * 64;
    int tid = threadIdx.x;
    int tm = tid & 15, tn = tid >> 4;
    int sr = tid >> 3, skq = tid & 7;
    float acc[4][4] = {};
    for (int k0 = 0; k0 < K; k0 += 32) {
        __syncthreads();
        #pragma unroll
        for (int p = 0; p < 2; ++p) {
            int r = sr + 32 * p;
            float4 av = *(const float4*)&A[(size_t)(m0 + r) * lda + k0 + skq * 4];
            as[skq*4+0][r] = av.x; as[skq*4+1][r] = av.y;
            as[skq*4+2][r] = av.z; as[skq*4+3][r] = av.w;
            float4 wv = *(const float4*)&W[(size_t)(n0 + r) * K + k0 + skq * 4];
            bs[skq*4+0][r] = wv.x; bs[skq*4+1][r] = wv.y;
            bs[skq*4+2][r] = wv.z; bs[skq*4+3][r] = wv.w;
        }
        __syncthreads();
        #pragma unroll 8
        for (int k = 0; k < 32; ++k) {
            float a4[4], b4[4];
            *(float4*)a4 = *(const float4*)&as[k][tm*4];
            *(float4*)b4 = *(const float4*)&bs[k][tn*4];
            #pragma unroll
            for (int i = 0; i < 4; ++i)
                #pragma unroll
                for (int j = 0; j < 4; ++j)
                    acc[i][j] = fmaf(a4[i], b4[j], acc[i][j]);
        }
    }
    float4 bv4 = *(const float4*)&bias[n0 + tn*4];
    #pragma unroll
    for (int i = 0; i < 4; ++i) {
        float4 c4;
        c4.x = acc[i][0] + bv4.x; c4.y = acc[i][1] + bv4.y;
        c4.z = acc[i][2] + bv4.z; c4.w = acc[i][3] + bv4.w;
        *(float4*)&C[(size_t)(m0 + tm*4 + i) * ldc + n0 + tn*4] = c4;
    }
}

// ---------------------------------------------------------------------------
__global__ void copy_visual_k(const float* __restrict__ src, float* __restrict__ dst)
{
    int idx = blockIdx.x * 256 + threadIdx.x;          // float4 index
    const int total = BATCH * (DIM / 4);
    for (; idx < total; idx += 512 * 256) {
        int b = idx / (DIM / 4), c = idx % (DIM / 4);
        ((float4*)dst)[(size_t)b * (1536 / 4) + c] = ((const float4*)src)[idx];
    }
}

// ---------------------------------------------------------------------------
__device__ __forceinline__ float block_sum(float v, float* red)
{
    #pragma unroll
    for (int o = 32; o; o >>= 1) v += __shfl_down(v, o);
    if ((threadIdx.x & 63) == 0) red[threadIdx.x >> 6] = v;
    __syncthreads();
    float r = red[0] + red[1] + red[2] + red[3];
    __syncthreads();
    return r;
}

__global__ __launch_bounds__(256) void ln_gelu_k(float* __restrict__ H,
        const float* __restrict__ g, const float* __restrict__ b)
{
    __shared__ float red[4];
    int row = blockIdx.x, tid = threadIdx.x;
    float* hr = H + (size_t)row * DIM;
    float v0 = hr[tid], v1 = hr[tid + 256], v2 = hr[tid + 512];
    float mu = block_sum(v0 + v1 + v2, red) * (1.0f / 768.0f);
    float d0 = v0 - mu, d1 = v1 - mu, d2 = v2 - mu;
    float var = block_sum(d0*d0 + d1*d1 + d2*d2, red) * (1.0f / 768.0f);
    float rinv = 1.0f / sqrtf(var + 1e-5f);
    #pragma unroll
    for (int q = 0; q < 3; ++q) {
        int d = tid + 256 * q;
        float dd = (q == 0 ? d0 : (q == 1 ? d1 : d2));
        float y = dd * rinv * g[d] + b[d];
        hr[d] = 0.5f * y * (1.0f + erff(y * 0.70710678118654752f));
    }
}

__global__ __launch_bounds__(256) void l2norm_bf_k(float* __restrict__ P,
        short* __restrict__ Pb)
{
    __shared__ float red[4];
    int row = blockIdx.x, tid = threadIdx.x;
    float* pr = P + (size_t)row * DIM;
    short* pb = Pb + (size_t)row * DIM;
    float v0 = pr[tid], v1 = pr[tid + 256], v2 = pr[tid + 512];
    float ss = block_sum(v0*v0 + v1*v1 + v2*v2, red);
    float inv = 1.0f / fmaxf(sqrtf(ss), 1e-12f);
    v0 *= inv; v1 *= inv; v2 *= inv;
    pr[tid] = v0; pr[tid + 256] = v1; pr[tid + 512] = v2;
    pb[tid] = f2bf(v0); pb[tid + 256] = f2bf(v1); pb[tid + 512] = f2bf(v2);
}

// ---------------------------------------------------------------------------
// prep_ans: fp64 row norm -> inv64[row]; unit-normalized bf16 rows into AB.
// ---------------------------------------------------------------------------
__global__ __launch_bounds__(256) void prep_ans_k(
    const float* __restrict__ ANS, int row0, int nrows,
    double* __restrict__ inv64, short* __restrict__ AB)
{
    int r = blockIdx.x * 4 + (threadIdx.x >> 6);
    if (r >= nrows) return;
    int row = row0 + r;
    int lane = threadIdx.x & 63;
    const float4* a4 = (const float4*)(ANS + (size_t)row * DIM);
    float4 x0 = a4[lane], x1 = a4[lane + 64], x2 = a4[lane + 128];
    double ss = (double)x0.x*x0.x + (double)x0.y*x0.y + (double)x0.z*x0.z + (double)x0.w*x0.w
              + (double)x1.x*x1.x + (double)x1.y*x1.y + (double)x1.z*x1.z + (double)x1.w*x1.w
              + (double)x2.x*x2.x + (double)x2.y*x2.y + (double)x2.z*x2.z + (double)x2.w*x2.w;
    #pragma unroll
    for (int o = 32; o; o >>= 1) ss += __shfl_xor(ss, o);
    double inv = 1.0 / fmax(sqrt(ss), 1e-12);
    if (lane == 0) inv64[row] = inv;
    float invf = (float)inv;
    short* ob = AB + (size_t)r * DIM;
    ushort4 o0, o1, o2;
    o0.x = (unsigned short)f2bf(x0.x*invf); o0.y = (unsigned short)f2bf(x0.y*invf);
    o0.z = (unsigned short)f2bf(x0.z*invf); o0.w = (unsigned short)f2bf(x0.w*invf);
    o1.x = (unsigned short)f2bf(x1.x*invf); o1.y = (unsigned short)f2bf(x1.y*invf);
    o1.z = (unsigned short)f2bf(x1.z*invf); o1.w = (unsigned short)f2bf(x1.w*invf);
    o2.x = (unsigned short)f2bf(x2.x*invf); o2.y = (unsigned short)f2bf(x2.y*invf);
    o2.z = (unsigned short)f2bf(x2.z*invf); o2.w = (unsigned short)f2bf(x2.w*invf);
    *(ushort4*)&ob[lane * 4]           = o0;
    *(ushort4*)&ob[(lane + 64) * 4]    = o1;
    *(ushort4*)&ob[(lane + 128) * 4]   = o2;
}

// ---------------------------------------------------------------------------
// prep_maskT: float mask [1024][128000] -> TRANSPOSED bits [4000][1024]
// ---------------------------------------------------------------------------
__global__ __launch_bounds__(256, 4) void prep_maskT_k(
    const float* __restrict__ mask, unsigned* __restrict__ bitsT)
{
    int r = blockIdx.x * 256 + threadIdx.x;
    int w0 = blockIdx.y * 40;
    const float* mr = mask + (size_t)r * NANS;
    for (int w = w0; w < w0 + 40; ++w) {
        const float4* p = (const float4*)(mr + w * 32);
        unsigned b = 0;
        #pragma unroll
        for (int q = 0; q < 8; ++q) {
            float4 v = p[q];
            b |= ((unsigned)(v.x != 0.f)) << (q*4+0);
            b |= ((unsigned)(v.y != 0.f)) << (q*4+1);
            b |= ((unsigned)(v.z != 0.f)) << (q*4+2);
            b |= ((unsigned)(v.w != 0.f)) << (q*4+3);
        }
        bitsT[(size_t)w * BATCH + r] = b;
    }
}

// ---------------------------------------------------------------------------
// gemmsel_k: fused MFMA GEMM (2-phase dbuf staging) + mask + per-(row,tile)
// top-10 via u32-packed max/min chains + shfl-pair bitonic merge.
// 256 thr / 4 waves; tile 128 answers x 128 batch; BK=32; 24 K-steps.
// ---------------------------------------------------------------------------
__global__ __launch_bounds__(256, 2) void gemmsel_k(
    const short* __restrict__ Pb,       // [1024][768] unit-norm bf16
    const short* __restrict__ AB,       // chunk rows, unit-norm bf16
    const unsigned* __restrict__ bitsT, // [4000][1024]
    unsigned* __restrict__ ck,          // [1024][1000*10] packed u32 keys
    int t128_0, int nt128)
{
    __shared__ __align__(16) char smem[33792];
    // staging: 2 bufs x (A [128][32] + B [128][32]) shorts
    float* scl = (float*)smem;                  // epilogue reuse: [64][132]

    int bid = blockIdx.x;
    int v = (bid & 7) * nt128 + (bid >> 3);
    int at = v >> 3, bt = v & 7;
    int gt = t128_0 + at;                       // global 128-tile id
    int a0l = at * 128, b0 = bt * 128;

    int tid = threadIdx.x;
    int lane = tid & 63, wid = tid >> 6;
    int wm = wid & 1, wn = wid >> 1;            // 2x2 wave grid of 64x64
    int lr = lane & 15, lg = lane >> 4;

    const char* gA0 = (const char*)(AB + (size_t)(a0l + (tid >> 2)) * DIM + (tid & 3) * 8);
    const char* gA1 = (const char*)(AB + (size_t)(a0l + 64 + (tid >> 2)) * DIM + (tid & 3) * 8);
    const char* gB0 = (const char*)(Pb + (size_t)(b0 + (tid >> 2)) * DIM + (tid & 3) * 8);
    const char* gB1 = (const char*)(Pb + (size_t)(b0 + 64 + (tid >> 2)) * DIM + (tid & 3) * 8);

    f32x4 acc[4][4];
    #pragma unroll
    for (int i = 0; i < 4; ++i)
        #pragma unroll
        for (int j = 0; j < 4; ++j)
            acc[i][j] = (f32x4){0.f, 0.f, 0.f, 0.f};

    // prologue: stage kt=0 into buf 0
    {
        char* la = smem + tid * 16;
        gload16(gA0, la);
        gload16(gA1, la + 4096);
        gload16(gB0, la + 16384);
        gload16(gB1, la + 20480);
    }
    __syncthreads();

    int buf = 0;
    for (int kt = 0; kt < 24; ++kt) {
        if (kt < 23) {                          // stage next tile into buf^1
            int kb = (kt + 1) * 64;
            char* la = smem + (buf ^ 1) * 8192 + tid * 16;
            gload16(gA0 + kb, la);
            gload16(gA1 + kb, la + 4096);
            gload16(gB0 + kb, la + 16384);
            gload16(gB1 + kb, la + 20480);
        }
        const short* a_sh = (const short*)(smem + buf * 8192);
        const short* b_sh = (const short*)(smem + 16384 + buf * 8192);
        bf16x8 af[4], bg[4];
        #pragma unroll
        for (int mt = 0; mt < 4; ++mt)
            af[mt] = *(const bf16x8*)(a_sh + (wm*64 + mt*16 + lr) * 32 + lg*8);
        #pragma unroll
        for (int nt = 0; nt < 4; ++nt)
            bg[nt] = *(const bf16x8*)(b_sh + (wn*64 + nt*16 + lr) * 32 + lg*8);
        #pragma unroll
        for (int mt = 0; mt < 4; ++mt)
            #pragma unroll
            for (int nt = 0; nt < 4; ++nt)
                acc[mt][nt] = __builtin_amdgcn_mfma_f32_16x16x32_bf16(
                    af[mt], bg[nt], acc[mt][nt], 0, 0, 0);
        __syncthreads();                        // drains next-tile loads too
        buf ^= 1;
    }

    // ---- epilogue: bitmask + per-column top-10, u32 keys in named regs ----
    Top10k tp;
    t10k_init(tp);
    int col = tid >> 1, qt = tid & 1;           // pair lanes share a column
    int qoff = qt * 32;

    for (int c = 0; c < 2; ++c) {               // 64-answer chunks
        __syncthreads();
        if (wm == c) {                          // 2 waves dump their quadrants
            #pragma unroll
            for (int nt = 0; nt < 4; ++nt) {
                int lcol = wn * 64 + nt * 16 + lr;
                #pragma unroll
                for (int mt = 0; mt < 4; ++mt) {
                    int lrow = mt * 16 + lg * 4;
                    scl[(lrow + 0) * 132 + lcol] = acc[mt][nt][0];
                    scl[(lrow + 1) * 132 + lcol] = acc[mt][nt][1];
                    scl[(lrow + 2) * 132 + lcol] = acc[mt][nt][2];
                    scl[(lrow + 3) * 132 + lcol] = acc[mt][nt][3];
                }
            }
        }
        __syncthreads();
        unsigned wv = bitsT[(size_t)(gt * 4 + c * 2 + qt) * BATCH + b0 + col];
        unsigned lobc = (unsigned)(127 - c * 64 - qoff);   // 127 - local base
        #pragma unroll
        for (int i = 0; i < 32; ++i) {
            float sc = scl[(qoff + i) * 132 + col];
            sc = ((wv >> i) & 1u) ? sc : 0.0f;
            unsigned key = (f2sort(sc) & 0xFFFFFF80u) | (lobc - (unsigned)i);
            t10k_ins(tp, key);
        }
    }

    // pair merge: top-10 of two sorted-desc 10-lists = {max(A[i], B[9-i])}
    unsigned q0 = __shfl_xor(tp.k0, 1), q1 = __shfl_xor(tp.k1, 1);
    unsigned q2 = __shfl_xor(tp.k2, 1), q3 = __shfl_xor(tp.k3, 1);
    unsigned q4 = __shfl_xor(tp.k4, 1), q5 = __shfl_xor(tp.k5, 1);
    unsigned q6 = __shfl_xor(tp.k6, 1), q7 = __shfl_xor(tp.k7, 1);
    unsigned q8 = __shfl_xor(tp.k8, 1), q9 = __shfl_xor(tp.k9, 1);
    if (qt == 0) {
        unsigned* dst = ck + (size_t)(b0 + col) * (NT128 * 10) + (size_t)gt * 10;
        dst[0] = umaxu(tp.k0, q9);
        dst[1] = umaxu(tp.k1, q8);
        dst[2] = umaxu(tp.k2, q7);
        dst[3] = umaxu(tp.k3, q6);
        dst[4] = umaxu(tp.k4, q5);
        dst[5] = umaxu(tp.k5, q4);
        dst[6] = umaxu(tp.k6, q3);
        dst[7] = umaxu(tp.k7, q2);
        dst[8] = umaxu(tp.k8, q1);
        dst[9] = umaxu(tp.k9, q0);
    }
}

// ---------------------------------------------------------------------------
// merge_rescore5: stream row's 10000 u32 keys (coalesced) -> per-thread
// top-16 of (key<<32)|pos -> LDS 4096 -> global top-16 -> fp64 rescore ->
// final top-10 + gather.  idx = (pos/10)*128 + 127 - (key & 0x7F).
// ---------------------------------------------------------------------------
__global__ __launch_bounds__(256) void merge_rescore5_k(
    const unsigned* __restrict__ ck,
    const float* __restrict__ P, const float* __restrict__ ANS,
    const double* __restrict__ invn64, const float* __restrict__ mask,
    float* __restrict__ out)
{
    __shared__ u64    lk[4096];
    __shared__ u64    rrk[4];
    __shared__ int    rrp[4];
    __shared__ int    topi_s[16];
    __shared__ double tops_s[16];
    __shared__ int    fin_s[10];
    int row = blockIdx.x, tid = threadIdx.x;

    Top16u t;
    t16u_init(t);
    const unsigned* ckr = ck + (size_t)row * (NT128 * 10);
    for (int j = tid; j < NT128 * 10; j += 256)
        t16u_ins(t, ((u64)ckr[j] << 32) | (unsigned)j);
    {
        int o = tid * 16;
        lk[o+0]=t.k0;  lk[o+1]=t.k1;  lk[o+2]=t.k2;  lk[o+3]=t.k3;
        lk[o+4]=t.k4;  lk[o+5]=t.k5;  lk[o+6]=t.k6;  lk[o+7]=t.k7;
        lk[o+8]=t.k8;  lk[o+9]=t.k9;  lk[o+10]=t.k10; lk[o+11]=t.k11;
        lk[o+12]=t.k12; lk[o+13]=t.k13; lk[o+14]=t.k14; lk[o+15]=t.k15;
    }
    __syncthreads();

    for (int it = 0; it < 16; ++it) {
        u64 bk = 0; int bp = -1;
        for (int j = tid; j < 4096; j += 256) {
            u64 k = lk[j];
            if (k > bk) { bk = k; bp = j; }
        }
        #pragma unroll
        for (int o = 32; o; o >>= 1) {
            u64 ok = __shfl_down(bk, o);
            int op = __shfl_down(bp, o);
            if (ok > bk) { bk = ok; bp = op; }
        }
        if ((tid & 63) == 0) { rrk[tid >> 6] = bk; rrp[tid >> 6] = bp; }
        __syncthreads();
        if (tid == 0) {
            for (int w = 1; w < 4; ++w)
                if (rrk[w] > bk) { bk = rrk[w]; bp = rrp[w]; }
            unsigned key = (unsigned)(bk >> 32);
            int pos = (int)(bk & 0xffffffffull);
            topi_s[it] = (pos / 10) * 128 + 127 - (int)(key & 0x7Fu);
            lk[bp] = 0;
        }
        __syncthreads();
    }

    // fp64 rescore: 16 threads per candidate
    int c = tid >> 4, part = tid & 15;
    int aidx = topi_s[c];
    const float4* p4 = (const float4*)(P + (size_t)row * DIM);
    const float4* a4 = (const float4*)(ANS + (size_t)aidx * DIM);
    double sum = 0.0;
    #pragma unroll
    for (int i = 0; i < 12; ++i) {
        float4 pv = p4[part * 12 + i];
        float4 av = a4[part * 12 + i];
        sum += (double)pv.x * av.x + (double)pv.y * av.y
             + (double)pv.z * av.z + (double)pv.w * av.w;
    }
    #pragma unroll
    for (int o = 8; o; o >>= 1) sum += __shfl_down(sum, o, 16);
    if (part == 0) {
        float m = mask[(size_t)row * NANS + aidx];
        tops_s[c] = sum * invn64[aidx] * (double)m;
    }
    __syncthreads();

    if (tid == 0) {
        unsigned used = 0;
        for (int k = 0; k < 10; ++k) {
            int bj = -1;
            for (int j = 0; j < 16; ++j) {
                if (used & (1u << j)) continue;
                if (bj < 0 || tops_s[j] > tops_s[bj] ||
                    (tops_s[j] == tops_s[bj] && topi_s[j] < topi_s[bj])) bj = j;
            }
            used |= 1u << bj;
            out[(size_t)row * 10 + k] = (float)tops_s[bj];
            out[10240 + (size_t)row * 10 + k] = (float)topi_s[bj];
            fin_s[k] = topi_s[bj];
        }
    }
    __syncthreads();

    for (int k = 0; k < 10; ++k) {
        int id = fin_s[k];
        const float* arow = ANS + (size_t)id * DIM;
        float* orow = out + 20480 + ((size_t)(row * 10 + k)) * DIM;
        for (int d = tid; d < DIM; d += 256) orow[d] = arow[d];
    }
}

// ---------------------------------------------------------------------------
extern "C" void kernel_launch(void* const* d_in, const int* in_sizes, int n_in,
                              void* d_out, int out_size, void* d_ws, size_t ws_size,
                              hipStream_t stream)
{
    (void)in_sizes; (void)n_in; (void)out_size;
    const float* visual = (const float*)d_in[0];
    const float* mask   = (const float*)d_in[2];
    const float* ans    = (const float*)d_in[3];
    const float* wv = (const float*)d_in[8];
    const float* bv = (const float*)d_in[9];
    const float* wo = (const float*)d_in[10];
    const float* bo = (const float*)d_in[11];
    const float* fw = (const float*)d_in[12];
    const float* fb = (const float*)d_in[13];
    const float* lg = (const float*)d_in[14];
    const float* lb = (const float*)d_in[15];
    const float* sw = (const float*)d_in[16];
    const float* sb = (const float*)d_in[17];
    float* out = (float*)d_out;

    // ---- workspace: persistent first; transient upstream + AB share tail ----
    char* w = (char*)d_ws;
    float*    P      = (float*)w;    w += (size_t)BATCH * DIM * 4;          // 3.1 MB
    short*    Pb     = (short*)w;    w += (size_t)BATCH * DIM * 2;          // 1.6 MB
    double*   invn64 = (double*)w;   w += (size_t)NANS * 8;                 // 1.0 MB
    unsigned* ck     = (unsigned*)w; w += (size_t)BATCH * NT128 * 10 * 4;   // 41 MB
    unsigned* bitsT  = (unsigned*)w; w += (size_t)NWORDS * BATCH * 4;       // 16.4 MB
    char*     tail   = w;
    float*    fused_in = (float*)tail;
    float*    v        = fused_in + (size_t)BATCH * 1536;
    float*    h        = v + (size_t)BATCH * DIM;
    short*    AB       = (short*)tail;  // reuses upstream transients after death

    size_t ab_t = (size_t)128 * DIM * 2;        // 196608 B per 128-tile
    size_t used = (size_t)(tail - (char*)d_ws);
    size_t avail = (ws_size > used) ? (ws_size - used) : ab_t;
    int CT = (int)(avail / ab_t);               // tiles per chunk
    if (CT < 1) CT = 1;
    if (CT > NT128) CT = NT128;
    int nch = (NT128 + CT - 1) / CT;

    copy_visual_k<<<512, 256, 0, stream>>>(visual, fused_in);
    gemm_bias_k<<<dim3(16, 12), 256, 0, stream>>>(visual, DIM, wv, bv, v, DIM, DIM);
    gemm_bias_k<<<dim3(16, 12), 256, 0, stream>>>(v, DIM, wo, bo, fused_in + DIM, 1536, DIM);
    gemm_bias_k<<<dim3(16, 12), 256, 0, stream>>>(fused_in, 1536, fw, fb, h, DIM, 1536);
    ln_gelu_k<<<BATCH, 256, 0, stream>>>(h, lg, lb);
    gemm_bias_k<<<dim3(16, 12), 256, 0, stream>>>(h, DIM, sw, sb, P, DIM, DIM);
    l2norm_bf_k<<<BATCH, 256, 0, stream>>>(P, Pb);
    prep_maskT_k<<<dim3(4, 100), 256, 0, stream>>>(mask, bitsT);
    // ---- upstream transients dead from here; AB reuses the tail ----

    for (int ch = 0; ch < nch; ++ch) {
        int t0 = ch * CT;
        int n = NT128 - t0; if (n > CT) n = CT;
        int nrows = n * 128;
        prep_ans_k<<<(nrows + 3) / 4, 256, 0, stream>>>(ans, t0 * 128, nrows,
                                                        invn64, AB);
        gemmsel_k<<<n * 8, 256, 0, stream>>>(Pb, AB, bitsT, ck, t0, n);
    }

    merge_rescore5_k<<<BATCH, 256, 0, stream>>>(ck, P, ans, invn64, mask, out);
}